// Round 5
// baseline (263.348 us; speedup 1.0000x reference)
//
#include <hip/hip_runtime.h>
#include <cstdint>
#include <cstddef>

// ALiBi MHA, MI355X/gfx950. fp16 MFMA (16x16x32) pipeline.
// R9 = R8 hardened (R8 bench: container failed twice, no counters; suspect
// either infra or prologue hand-counted vmcnt assumptions):
//  - Prologues now drain s_waitcnt vmcnt(0) unconditionally (one-time/block).
//    Counted waits remain ONLY in steady-state loops where the outstanding-op
//    accounting is exact (gl_lds builtins, program-ordered).
//  - sched_barrier(0) after the GEMM loop's counted waitcnt (anti-hoist).
//  - flash: reg-staged depth-2 K/V pipeline (global->VGPR for t+2 issued under
//    t's compute; VGPR->LDS ds_write for t+1; raw s_barrier + lgkmcnt(0) per
//    iter; NO vmcnt(0) drain in loop). LDS 40KB => 4 blocks/CU.
//  - GEMMs: 3-buffer gl_lds depth-2 pipeline, counted s_waitcnt vmcnt(4)
//    (never 0 mid-loop) + raw barriers.

typedef unsigned short u16;
typedef __attribute__((ext_vector_type(8))) _Float16 half8;
typedef __attribute__((ext_vector_type(8))) unsigned short ushort8;
typedef __attribute__((ext_vector_type(4))) float f32x4;

#define DEVI static __device__ __forceinline__
#define MFMA16(a, b, c) __builtin_amdgcn_mfma_f32_16x16x32_f16(a, b, c, 0, 0, 0)

DEVI u16 f2h_bits(float f) {
  _Float16 h = (_Float16)f;  // v_cvt_f16_f32, RNE
  union { _Float16 h; u16 u; } v; v.h = h;
  return v.u;
}

// async global->LDS, 16B per lane. LDS dest must be wave-uniform base + lane*16.
DEVI void gl_lds16(const u16* g, u16* l) {
  __builtin_amdgcn_global_load_lds(
      (const __attribute__((address_space(1))) void*)g,
      (__attribute__((address_space(3))) void*)l, 16, 0, 0);
}

#define LGKM0() __asm__ volatile("s_waitcnt lgkmcnt(0)" ::: "memory")
#define VM0()   __asm__ volatile("s_waitcnt vmcnt(0)" ::: "memory")
#define BARRIER()                       \
  do {                                  \
    __builtin_amdgcn_s_barrier();       \
    __asm__ volatile("" ::: "memory");  \
  } while (0)

// ---------------- cast fp32 -> fp16 bits, 4 elems/thread, z selects tensor ----------------
__global__ __launch_bounds__(256) void cast3_h(const float* __restrict__ in0,
                                               const float* __restrict__ in1,
                                               const float* __restrict__ in2,
                                               u16* __restrict__ o0,
                                               u16* __restrict__ o1,
                                               u16* __restrict__ o2, int n) {
  const float* in = blockIdx.z == 0 ? in0 : (blockIdx.z == 1 ? in1 : in2);
  u16* out = blockIdx.z == 0 ? o0 : (blockIdx.z == 1 ? o1 : o2);
  int i = (blockIdx.x * 256 + threadIdx.x) * 4;
  if (i + 3 < n) {
    const float4 v = *(const float4*)(in + i);
    ushort4 o;
    o.x = f2h_bits(v.x); o.y = f2h_bits(v.y); o.z = f2h_bits(v.z); o.w = f2h_bits(v.w);
    *(ushort4*)(out + i) = o;
  }
}

// ---------------- Wt[n][k] = (f16)W[k][n], 1024x1024, LDS-tiled, z selects W ----------------
__global__ __launch_bounds__(256) void transpose4_h(
    const float* __restrict__ W0, const float* __restrict__ W1,
    const float* __restrict__ W2, const float* __restrict__ W3,
    u16* __restrict__ T0, u16* __restrict__ T1, u16* __restrict__ T2,
    u16* __restrict__ T3) {
  const float* W = blockIdx.z == 0 ? W0 : (blockIdx.z == 1 ? W1 : (blockIdx.z == 2 ? W2 : W3));
  u16* Wt = blockIdx.z == 0 ? T0 : (blockIdx.z == 1 ? T1 : (blockIdx.z == 2 ? T2 : T3));
  __shared__ float tile[32][33];
  const int bx = blockIdx.x * 32;
  const int by = blockIdx.y * 32;
  const int x = threadIdx.x & 31;
  const int y0 = threadIdx.x >> 5;  // 0..7
#pragma unroll
  for (int i = y0; i < 32; i += 8)
    tile[i][x] = W[(size_t)(by + i) * 1024 + bx + x];
  __syncthreads();
#pragma unroll
  for (int i = y0; i < 32; i += 8)
    Wt[(size_t)(bx + i) * 1024 + by + x] = f2h_bits(tile[x][i]);
}

// ---------------- GEMM body: C[4096x1024] = A[4096x1024] x Bt[1024x1024]^T ----------------
// 3-buffer depth-2 gl_lds pipeline: stage(kt+2) issued while computing kt;
// s_waitcnt vmcnt(4) (leave newest tile in flight) before each raw barrier.
// 32-elem rows in LDS = 4 chunks of 8; chunk swizzle p = c ^ ((row>>1)&3).
// mode 0: fp32 out; mode 1: fp16 out row-major; mode 2: fp16 out as Vt[b][h][d][s]
DEVI void gemm_body(const u16* __restrict__ A, const u16* __restrict__ Bt,
                    void* __restrict__ Cout, int mode, u16* As, u16* Bs) {
  constexpr int K = 1024, N = 1024;
  const int t = threadIdx.x;
  const int lane = t & 63;
  const int quad = lane >> 4;
  const int l16 = lane & 15;
  const int wid = t >> 6;
  const int mBase = blockIdx.y * 128;
  const int nBase = blockIdx.x * 128;
  const int wM = (wid >> 1) * 64;
  const int wN = (wid & 1) * 64;
  const int aswz = (quad ^ ((l16 >> 1) & 3)) << 3;  // frag-read physical col

  f32x4 acc[4][4];
#pragma unroll
  for (int i = 0; i < 4; ++i)
#pragma unroll
    for (int j = 0; j < 4; ++j) acc[i][j] = (f32x4){0.f, 0.f, 0.f, 0.f};

  // staging: 128x32 f16 tile = 8KB = 512 16B-chunks / 256 thr, A and B each
  auto stage = [&](int kt, u16* Ad, u16* Bd) {
#pragma unroll
    for (int i = 0; i < 2; ++i) {
      const int ci = i * 256 + t;
      const int row = ci >> 2;                              // 4 chunks per 32-elem row
      const int col = (((ci & 3) ^ ((ci >> 3) & 3)) << 3);  // staging-side swizzle
      gl_lds16(A + (size_t)(mBase + row) * K + kt * 32 + col, Ad + ci * 8);
      gl_lds16(Bt + (size_t)(nBase + row) * K + kt * 32 + col, Bd + ci * 8);
    }
  };

  u16 *a0 = As, *a1 = As + 4096, *a2 = As + 8192;
  u16 *b0 = Bs, *b1 = Bs + 4096, *b2 = Bs + 8192;

  // prologue: stage tiles 0,1; unconditional full drain (once per block)
  stage(0, a0, b0);
  stage(1, a1, b1);
  VM0();
  BARRIER();

  for (int kt = 0; kt < K / 32; ++kt) {
    if (kt + 2 < K / 32) stage(kt + 2, a2, b2);

    half8 a[4], b[4];
#pragma unroll
    for (int mi = 0; mi < 4; ++mi)
      a[mi] = *(const half8*)(a0 + (wM + mi * 16 + l16) * 32 + aswz);
#pragma unroll
    for (int ni = 0; ni < 4; ++ni)
      b[ni] = *(const half8*)(b0 + (wN + ni * 16 + l16) * 32 + aswz);
#pragma unroll
    for (int mi = 0; mi < 4; ++mi)
#pragma unroll
      for (int ni = 0; ni < 4; ++ni)
        acc[mi][ni] = MFMA16(a[mi], b[ni], acc[mi][ni]);

    if (kt + 1 < K / 32) {
      // outstanding gl_lds here: kt+1's 4 (+ kt+2's 4 if staged).
      if (kt + 2 < K / 32)
        __asm__ volatile("s_waitcnt vmcnt(4)" ::: "memory");  // kt+1 landed, kt+2 flying
      else
        VM0();  // tail: last tile landed
      __builtin_amdgcn_sched_barrier(0);
      LGKM0();  // own frag ds_reads done -> safe for others to overwrite old buf
      BARRIER();
    }
    u16* ta = a0; a0 = a1; a1 = a2; a2 = ta;
    u16* tb = b0; b0 = b1; b1 = b2; b2 = tb;
  }

  // epilogue. C/D layout: row = quad*4 + reg, col = lane&15 (m89/m91-verified)
#pragma unroll
  for (int mi = 0; mi < 4; ++mi) {
#pragma unroll
    for (int ni = 0; ni < 4; ++ni) {
#pragma unroll
      for (int r = 0; r < 4; ++r) {
        const int m = mBase + wM + mi * 16 + quad * 4 + r;
        const int n = nBase + wN + ni * 16 + l16;
        const float v = acc[mi][ni][r];
        if (mode == 0) {
          ((float*)Cout)[(size_t)m * N + n] = v;
        } else if (mode == 1) {
          ((u16*)Cout)[(size_t)m * N + n] = f2h_bits(v);
        } else {
          // Vt[(b*1024 + n)][s], b = m>>11, s = m&2047, S=2048
          ((u16*)Cout)[(((size_t)(m >> 11) * 1024 + n) << 11) | (size_t)(m & 2047)] = f2h_bits(v);
        }
      }
    }
  }
}

__global__ __launch_bounds__(256) void proj_qkv(
    const u16* __restrict__ qb, const u16* __restrict__ kb, const u16* __restrict__ vb,
    const u16* __restrict__ Wqt, const u16* __restrict__ Wkt, const u16* __restrict__ Wvt,
    u16* __restrict__ Qp, u16* __restrict__ Kp, u16* __restrict__ Vtp) {
  __shared__ u16 As[3 * 128 * 32];  // 24 KB (3 buffers)
  __shared__ u16 Bs[3 * 128 * 32];  // 24 KB
  const int z = blockIdx.z;
  const u16* A = z == 0 ? qb : (z == 1 ? kb : vb);
  const u16* Bt = z == 0 ? Wqt : (z == 1 ? Wkt : Wvt);
  void* C = z == 0 ? (void*)Qp : (z == 1 ? (void*)Kp : (void*)Vtp);
  gemm_body(A, Bt, C, z == 2 ? 2 : 1, As, Bs);
}

__global__ __launch_bounds__(256) void gemm_out(const u16* __restrict__ Ao,
                                                const u16* __restrict__ Wot,
                                                float* __restrict__ out) {
  __shared__ u16 As[3 * 128 * 32];
  __shared__ u16 Bs[3 * 128 * 32];
  gemm_body(Ao, Wot, out, 0, As, Bs);
}

// ---------------- flash attention + ALiBi, no-max exp2 softmax ----------------
// grid (32 qtiles, 16 heads heavy-first, 2 batch), 256 thr = 4 waves x 16 q-rows,
// K-tile 64. Reg-staged depth-2 K/V pipeline: tile t+2 global->VGPR issued at
// top of iter t, tile t+1 VGPR->LDS (ds_write) under iter t's compute, raw
// s_barrier + lgkmcnt(0) per iter. In-loop vmcnt waits are compiler-generated
// from the VGPR data deps (counted, never 0). Q register-resident.
// Chunk swizzle c ^ (row&7) on K/V/Q (applied on the global-read side),
// undone at frag-read time -> 2-way banks.
// ALiBi skip: tile dropped when sl2*dist > 30 (neglected mass < 2^-15 of l).
__global__ __launch_bounds__(256, 4) void flash_alibi(
    const u16* __restrict__ Qg, const u16* __restrict__ Kg,
    const u16* __restrict__ Vtg, u16* __restrict__ Og) {
  constexpr int S = 2048, Dm = 1024, HD = 64;
  __shared__ u16 Ks[2][64 * 64];   // 16 KB double-buffered
  __shared__ u16 Vs[2][64 * 64];   // 16 KB double-buffered, Vs[d][k]
  __shared__ u16 Ps[64 * 64];      // 8 KB; stages Q in prologue, then P tiles
  const int t = threadIdx.x, lane = t & 63, wid = t >> 6;  // wid 0..3
  const int quad = lane >> 4, l16 = lane & 15;
  const int qt = blockIdx.x, b = blockIdx.z;
  const int h = 15 - blockIdx.y;  // heavy heads (many k-tiles) dispatch first
  const int qBase = qt * 64;
  const size_t qRow0 = (size_t)b * S + qBase;
  const float sl2 = __builtin_amdgcn_exp2f(-0.5f * (float)(h + 1)) * 1.44269504f;
  const float sc2 = 0.125f * 1.44269504f;  // (1/sqrt(64))*log2(e)
  const int Di = (int)(30.0f / sl2);
  const int ktLo = max(0, (qBase - Di) >> 6);
  const int ktHi = min(31, (qBase + 63 + Di) >> 6);
  const int cswz = ((l16 & 7) << 3);  // frag-read chunk xor (x8 elems)
  const int pRowBase = wid * 16;      // this wave's private 16-row P region

  // per-thread staging geometry (constant across tiles)
  const u16* Kb0 = Kg + (size_t)b * S * Dm + h * HD;        // + (kB+row)*Dm + col
  const u16* Vb0 = Vtg + ((size_t)(b * 16 + h) * HD) * S;   // + row*S + kB + col

  // prologue: Q tile -> Ps via gl_lds (64 rows x 8 chunks = 512 chunks / 256 thr)
#pragma unroll
  for (int i = 0; i < 2; ++i) {
    const int ci = i * 256 + t;
    const int row = ci >> 3, col = (((ci & 7) ^ (row & 7)) << 3);
    gl_lds16(Qg + (qRow0 + row) * Dm + h * HD + col, Ps + ci * 8);
  }

  // reg-staging helpers
  ushort8 krA[2], vrA[2], krB[2], vrB[2];
  auto fa_load = [&](int kB, ushort8* kr, ushort8* vr) {
#pragma unroll
    for (int i = 0; i < 2; ++i) {
      const int ci = i * 256 + t;
      const int row = ci >> 3, col = (((ci & 7) ^ (row & 7)) << 3);
      kr[i] = *(const ushort8*)(Kb0 + (size_t)(kB + row) * Dm + col);
      vr[i] = *(const ushort8*)(Vb0 + (size_t)row * S + kB + col);
    }
  };
  auto fa_write = [&](u16* Kd, u16* Vd, const ushort8* kr, const ushort8* vr) {
#pragma unroll
    for (int i = 0; i < 2; ++i) {
      const int ci = i * 256 + t;
      *(ushort8*)(Kd + ci * 8) = kr[i];
      *(ushort8*)(Vd + ci * 8) = vr[i];
    }
  };

  // prologue staging: B-set <- ktLo; A-set <- ktLo+1 (if any); buf0 <- B-set.
  // Unconditional full drain once per block (covers Q gl_lds + all reg loads,
  // no assumptions about compiler load splitting/ordering).
  fa_load(ktLo * 64, krB, vrB);
  if (ktLo + 1 <= ktHi) fa_load((ktLo + 1) * 64, krA, vrA);
  fa_write(Ks[0], Vs[0], krB, vrB);
  VM0();
  LGKM0();
  BARRIER();

  // ALiBi row bias (constant over kt): bi[r] = sl2 * global_q_row
  float bi[4];
#pragma unroll
  for (int r = 0; r < 4; ++r)
    bi[r] = sl2 * (float)(qBase + wid * 16 + quad * 4 + r);

  f32x4 acc_o[4];
#pragma unroll
  for (int nd = 0; nd < 4; ++nd) acc_o[nd] = (f32x4){0.f, 0.f, 0.f, 0.f};
  float lrow[4] = {0.f, 0.f, 0.f, 0.f};

  // Q -> registers. Wave w reads only rows [16w,16w+16) of Ps == its own P
  // region; same-wave DS ops to the same addresses are ordered, so these reads
  // complete before this wave's later P stores to the same region.
  half8 aq[2];
#pragma unroll
  for (int ks = 0; ks < 2; ++ks) {
    const int ck = ((ks * 4 + quad) << 3) ^ cswz;
    aq[ks] = *(const half8*)(Ps + (pRowBase + l16) * HD + ck);
  }

  // compute one k-tile from LDS buffers Kb/Vb (Q frags from registers)
#define FA_COMPUTE(kB_, Kb_, Vb_)                                               \
  do {                                                                          \
    f32x4 s4[4];                                                                \
    _Pragma("unroll")                                                           \
    for (int ni = 0; ni < 4; ++ni) s4[ni] = (f32x4){0.f, 0.f, 0.f, 0.f};        \
    __builtin_amdgcn_s_setprio(1);                                              \
    _Pragma("unroll")                                                           \
    for (int ks = 0; ks < 2; ++ks) {                                            \
      const int ck = ((ks * 4 + quad) << 3) ^ cswz;                             \
      _Pragma("unroll")                                                         \
      for (int ni = 0; ni < 4; ++ni) {                                          \
        const half8 bk = *(const half8*)((Kb_) + (ni * 16 + l16) * HD + ck);    \
        s4[ni] = MFMA16(aq[ks], bk, s4[ni]);                                    \
      }                                                                         \
    }                                                                           \
    __builtin_amdgcn_s_setprio(0);                                              \
    float bj[4];                                                                \
    _Pragma("unroll")                                                           \
    for (int ni = 0; ni < 4; ++ni) bj[ni] = sl2 * (float)((kB_) + ni * 16 + l16); \
    _Pragma("unroll")                                                           \
    for (int r = 0; r < 4; ++r) {                                               \
      float rs = 0.f;                                                           \
      const int prow = (pRowBase + quad * 4 + r) * 64;                          \
      _Pragma("unroll")                                                         \
      for (int ni = 0; ni < 4; ++ni) {                                          \
        const float d = fabsf(bi[r] - bj[ni]);                                  \
        const float p = __builtin_amdgcn_exp2f(s4[ni][r] * sc2 - d);            \
        rs += p;                                                                \
        Ps[prow + ((ni * 16 + l16) ^ (quad << 4))] = f2h_bits(p);               \
      }                                                                         \
      lrow[r] += rs;                                                            \
    }                                                                           \
    LGKM0(); /* wave-local: own P writes drained (P region is per-wave) */      \
    __builtin_amdgcn_s_setprio(1);                                              \
    _Pragma("unroll")                                                           \
    for (int ks = 0; ks < 2; ++ks) {                                            \
      const int pk = (ks * 32 + quad * 8) ^ ((l16 & 12) << 2);                  \
      const int ck = ((ks * 4 + quad) << 3) ^ cswz;                             \
      const half8 aP = *(const half8*)(Ps + (pRowBase + l16) * 64 + pk);        \
      _Pragma("unroll")                                                         \
      for (int nd = 0; nd < 4; ++nd) {                                          \
        const half8 bv = *(const half8*)((Vb_) + (nd * 16 + l16) * HD + ck);    \
        acc_o[nd] = MFMA16(aP, bv, acc_o[nd]);                                  \
      }                                                                         \
    }                                                                           \
    __builtin_amdgcn_s_setprio(0);                                              \
  } while (0)

  // main loop, 2x unrolled (A/B reg sets and buf0/buf1 alternate; all static).
  // ds_write of tile t+1 depends on its reg loads -> compiler inserts a COUNTED
  // vmcnt (leaving tile t+2's loads in flight). No full drain in the loop.
  int kt = ktLo;
  for (;;) {
    // phase 0: compute kt from buf0; A-set holds kt+1; load kt+2 into B-set
    if (kt + 2 <= ktHi) fa_load((kt + 2) * 64, krB, vrB);
    if (kt + 1 <= ktHi) fa_write(Ks[1], Vs[1], krA, vrA);
    FA_COMPUTE(kt * 64, Ks[0], Vs[0]);
    LGKM0();
    BARRIER();
    if (kt + 1 > ktHi) break;
    // phase 1: compute kt+1 from buf1; B-set holds kt+2; load kt+3 into A-set
    if (kt + 3 <= ktHi) fa_load((kt + 3) * 64, krA, vrA);
    if (kt + 2 <= ktHi) fa_write(Ks[0], Vs[0], krB, vrB);
    FA_COMPUTE((kt + 1) * 64, Ks[1], Vs[1]);
    LGKM0();
    BARRIER();
    if (kt + 2 > ktHi) break;
    kt += 2;
  }
#undef FA_COMPUTE

  // epilogue: reduce l across the 16 lanes sharing each row, O /= l, write f16
#pragma unroll
  for (int r = 0; r < 4; ++r) {
    float l = lrow[r];
    l += __shfl_xor(l, 1);
    l += __shfl_xor(l, 2);
    l += __shfl_xor(l, 4);
    l += __shfl_xor(l, 8);
    const float inv = 1.f / l;
    const int rloc = wid * 16 + quad * 4 + r;
#pragma unroll
    for (int nd = 0; nd < 4; ++nd)
      Og[(qRow0 + rloc) * Dm + h * HD + nd * 16 + l16] = f2h_bits(acc_o[nd][r] * inv);
  }
}

extern "C" void kernel_launch(void* const* d_in, const int* in_sizes, int n_in,
                              void* d_out, int out_size, void* d_ws, size_t ws_size,
                              hipStream_t stream) {
  const float* q  = (const float*)d_in[0];
  const float* k  = (const float*)d_in[1];
  const float* v  = (const float*)d_in[2];
  const float* Wq = (const float*)d_in[3];
  const float* Wk = (const float*)d_in[4];
  const float* Wv = (const float*)d_in[5];
  const float* Wo = (const float*)d_in[6];
  char* ws = (char*)d_ws;
  const size_t MB = 1ull << 20;
  // workspace map (64 MB total)
  u16* qb  = (u16*)(ws + 0 * MB);    // 8 MB  q fp16
  u16* kb  = (u16*)(ws + 8 * MB);    // 8 MB
  u16* vb  = (u16*)(ws + 16 * MB);   // 8 MB
  u16* Wqt = (u16*)(ws + 24 * MB);   // 2 MB  W^T fp16
  u16* Wkt = (u16*)(ws + 26 * MB);
  u16* Wvt = (u16*)(ws + 28 * MB);
  u16* Wot = (u16*)(ws + 30 * MB);
  u16* Qp  = (u16*)(ws + 32 * MB);   // 8 MB  Q proj [4096][1024]
  u16* Kp  = (u16*)(ws + 40 * MB);   // 8 MB
  u16* Vtp = (u16*)(ws + 48 * MB);   // 8 MB  V proj transposed [b][h][64][2048]
  u16* Ao  = (u16*)(ws + 56 * MB);   // 8 MB  attention out [4096][1024]

  const int n = 2 * 2048 * 1024;
  cast3_h<<<dim3(n / 1024, 1, 3), 256, 0, stream>>>(q, k, v, qb, kb, vb, n);
  transpose4_h<<<dim3(32, 32, 4), 256, 0, stream>>>(Wq, Wk, Wv, Wo, Wqt, Wkt, Wvt, Wot);
  proj_qkv<<<dim3(8, 32, 3), 256, 0, stream>>>(qb, kb, vb, Wqt, Wkt, Wvt, Qp, Kp, Vtp);
  flash_alibi<<<dim3(32, 16, 2), 256, 0, stream>>>(Qp, Kp, Vtp, Ao);
  gemm_out<<<dim3(8, 32), 256, 0, stream>>>(Ao, Wot, (float*)d_out);
}

// Round 6
// 258.966 us; speedup vs baseline: 1.0169x; 1.0169x over previous
//
#include <hip/hip_runtime.h>
#include <cstdint>
#include <cstddef>

// ALiBi MHA, MI355X/gfx950. fp16 MFMA (16x16x32) pipeline.
// R10 = R9 with the flash reg-staging SPILL FIXED (R9 counters: WRITE_SIZE
// 55MB + VGPR=64 => staging arrays went to scratch via pointer-passing).
//  - flash: depth-2 reg-staged K/V pipeline with NAMED ushort8 registers and
//    token-pasted macros (no local arrays, no pointers-to-locals) => SROA
//    keeps them in VGPRs. Compiler-counted vmcnt on the ds_write data deps;
//    only lgkmcnt(0)+s_barrier per phase; no full vmcnt drain in loop.
//  - GEMMs unchanged from R9 (3-buffer gl_lds, counted vmcnt(4); measured
//    neutral-to-slightly-positive vs R6).

typedef unsigned short u16;
typedef __attribute__((ext_vector_type(8))) _Float16 half8;
typedef __attribute__((ext_vector_type(8))) unsigned short ushort8;
typedef __attribute__((ext_vector_type(4))) float f32x4;

#define DEVI static __device__ __forceinline__
#define MFMA16(a, b, c) __builtin_amdgcn_mfma_f32_16x16x32_f16(a, b, c, 0, 0, 0)

DEVI u16 f2h_bits(float f) {
  _Float16 h = (_Float16)f;  // v_cvt_f16_f32, RNE
  union { _Float16 h; u16 u; } v; v.h = h;
  return v.u;
}

// async global->LDS, 16B per lane. LDS dest must be wave-uniform base + lane*16.
DEVI void gl_lds16(const u16* g, u16* l) {
  __builtin_amdgcn_global_load_lds(
      (const __attribute__((address_space(1))) void*)g,
      (__attribute__((address_space(3))) void*)l, 16, 0, 0);
}

#define LGKM0() __asm__ volatile("s_waitcnt lgkmcnt(0)" ::: "memory")
#define VM0()   __asm__ volatile("s_waitcnt vmcnt(0)" ::: "memory")
#define BARRIER()                       \
  do {                                  \
    __builtin_amdgcn_s_barrier();       \
    __asm__ volatile("" ::: "memory");  \
  } while (0)

// ---------------- cast fp32 -> fp16 bits, 4 elems/thread, z selects tensor ----------------
__global__ __launch_bounds__(256) void cast3_h(const float* __restrict__ in0,
                                               const float* __restrict__ in1,
                                               const float* __restrict__ in2,
                                               u16* __restrict__ o0,
                                               u16* __restrict__ o1,
                                               u16* __restrict__ o2, int n) {
  const float* in = blockIdx.z == 0 ? in0 : (blockIdx.z == 1 ? in1 : in2);
  u16* out = blockIdx.z == 0 ? o0 : (blockIdx.z == 1 ? o1 : o2);
  int i = (blockIdx.x * 256 + threadIdx.x) * 4;
  if (i + 3 < n) {
    const float4 v = *(const float4*)(in + i);
    ushort4 o;
    o.x = f2h_bits(v.x); o.y = f2h_bits(v.y); o.z = f2h_bits(v.z); o.w = f2h_bits(v.w);
    *(ushort4*)(out + i) = o;
  }
}

// ---------------- Wt[n][k] = (f16)W[k][n], 1024x1024, LDS-tiled, z selects W ----------------
__global__ __launch_bounds__(256) void transpose4_h(
    const float* __restrict__ W0, const float* __restrict__ W1,
    const float* __restrict__ W2, const float* __restrict__ W3,
    u16* __restrict__ T0, u16* __restrict__ T1, u16* __restrict__ T2,
    u16* __restrict__ T3) {
  const float* W = blockIdx.z == 0 ? W0 : (blockIdx.z == 1 ? W1 : (blockIdx.z == 2 ? W2 : W3));
  u16* Wt = blockIdx.z == 0 ? T0 : (blockIdx.z == 1 ? T1 : (blockIdx.z == 2 ? T2 : T3));
  __shared__ float tile[32][33];
  const int bx = blockIdx.x * 32;
  const int by = blockIdx.y * 32;
  const int x = threadIdx.x & 31;
  const int y0 = threadIdx.x >> 5;  // 0..7
#pragma unroll
  for (int i = y0; i < 32; i += 8)
    tile[i][x] = W[(size_t)(by + i) * 1024 + bx + x];
  __syncthreads();
#pragma unroll
  for (int i = y0; i < 32; i += 8)
    Wt[(size_t)(bx + i) * 1024 + by + x] = f2h_bits(tile[x][i]);
}

// ---------------- GEMM body: C[4096x1024] = A[4096x1024] x Bt[1024x1024]^T ----------------
// 3-buffer depth-2 gl_lds pipeline: stage(kt+2) issued while computing kt;
// s_waitcnt vmcnt(4) (leave newest tile in flight) before each raw barrier.
// 32-elem rows in LDS = 4 chunks of 8; chunk swizzle p = c ^ ((row>>1)&3).
// mode 0: fp32 out; mode 1: fp16 out row-major; mode 2: fp16 out as Vt[b][h][d][s]
DEVI void gemm_body(const u16* __restrict__ A, const u16* __restrict__ Bt,
                    void* __restrict__ Cout, int mode, u16* As, u16* Bs) {
  constexpr int K = 1024, N = 1024;
  const int t = threadIdx.x;
  const int lane = t & 63;
  const int quad = lane >> 4;
  const int l16 = lane & 15;
  const int wid = t >> 6;
  const int mBase = blockIdx.y * 128;
  const int nBase = blockIdx.x * 128;
  const int wM = (wid >> 1) * 64;
  const int wN = (wid & 1) * 64;
  const int aswz = (quad ^ ((l16 >> 1) & 3)) << 3;  // frag-read physical col

  f32x4 acc[4][4];
#pragma unroll
  for (int i = 0; i < 4; ++i)
#pragma unroll
    for (int j = 0; j < 4; ++j) acc[i][j] = (f32x4){0.f, 0.f, 0.f, 0.f};

  // staging: 128x32 f16 tile = 8KB = 512 16B-chunks / 256 thr, A and B each
  auto stage = [&](int kt, u16* Ad, u16* Bd) {
#pragma unroll
    for (int i = 0; i < 2; ++i) {
      const int ci = i * 256 + t;
      const int row = ci >> 2;                              // 4 chunks per 32-elem row
      const int col = (((ci & 3) ^ ((ci >> 3) & 3)) << 3);  // staging-side swizzle
      gl_lds16(A + (size_t)(mBase + row) * K + kt * 32 + col, Ad + ci * 8);
      gl_lds16(Bt + (size_t)(nBase + row) * K + kt * 32 + col, Bd + ci * 8);
    }
  };

  u16 *a0 = As, *a1 = As + 4096, *a2 = As + 8192;
  u16 *b0 = Bs, *b1 = Bs + 4096, *b2 = Bs + 8192;

  // prologue: stage tiles 0,1; unconditional full drain (once per block)
  stage(0, a0, b0);
  stage(1, a1, b1);
  VM0();
  BARRIER();

  for (int kt = 0; kt < K / 32; ++kt) {
    if (kt + 2 < K / 32) stage(kt + 2, a2, b2);

    half8 a[4], b[4];
#pragma unroll
    for (int mi = 0; mi < 4; ++mi)
      a[mi] = *(const half8*)(a0 + (wM + mi * 16 + l16) * 32 + aswz);
#pragma unroll
    for (int ni = 0; ni < 4; ++ni)
      b[ni] = *(const half8*)(b0 + (wN + ni * 16 + l16) * 32 + aswz);
#pragma unroll
    for (int mi = 0; mi < 4; ++mi)
#pragma unroll
      for (int ni = 0; ni < 4; ++ni)
        acc[mi][ni] = MFMA16(a[mi], b[ni], acc[mi][ni]);

    if (kt + 1 < K / 32) {
      // outstanding gl_lds here: kt+1's 4 (+ kt+2's 4 if staged).
      if (kt + 2 < K / 32)
        __asm__ volatile("s_waitcnt vmcnt(4)" ::: "memory");  // kt+1 landed, kt+2 flying
      else
        VM0();  // tail: last tile landed
      __builtin_amdgcn_sched_barrier(0);
      LGKM0();  // own frag ds_reads done -> safe for others to overwrite old buf
      BARRIER();
    }
    u16* ta = a0; a0 = a1; a1 = a2; a2 = ta;
    u16* tb = b0; b0 = b1; b1 = b2; b2 = tb;
  }

  // epilogue. C/D layout: row = quad*4 + reg, col = lane&15 (m89/m91-verified)
#pragma unroll
  for (int mi = 0; mi < 4; ++mi) {
#pragma unroll
    for (int ni = 0; ni < 4; ++ni) {
#pragma unroll
      for (int r = 0; r < 4; ++r) {
        const int m = mBase + wM + mi * 16 + quad * 4 + r;
        const int n = nBase + wN + ni * 16 + l16;
        const float v = acc[mi][ni][r];
        if (mode == 0) {
          ((float*)Cout)[(size_t)m * N + n] = v;
        } else if (mode == 1) {
          ((u16*)Cout)[(size_t)m * N + n] = f2h_bits(v);
        } else {
          // Vt[(b*1024 + n)][s], b = m>>11, s = m&2047, S=2048
          ((u16*)Cout)[(((size_t)(m >> 11) * 1024 + n) << 11) | (size_t)(m & 2047)] = f2h_bits(v);
        }
      }
    }
  }
}

__global__ __launch_bounds__(256) void proj_qkv(
    const u16* __restrict__ qb, const u16* __restrict__ kb, const u16* __restrict__ vb,
    const u16* __restrict__ Wqt, const u16* __restrict__ Wkt, const u16* __restrict__ Wvt,
    u16* __restrict__ Qp, u16* __restrict__ Kp, u16* __restrict__ Vtp) {
  __shared__ u16 As[3 * 128 * 32];  // 24 KB (3 buffers)
  __shared__ u16 Bs[3 * 128 * 32];  // 24 KB
  const int z = blockIdx.z;
  const u16* A = z == 0 ? qb : (z == 1 ? kb : vb);
  const u16* Bt = z == 0 ? Wqt : (z == 1 ? Wkt : Wvt);
  void* C = z == 0 ? (void*)Qp : (z == 1 ? (void*)Kp : (void*)Vtp);
  gemm_body(A, Bt, C, z == 2 ? 2 : 1, As, Bs);
}

__global__ __launch_bounds__(256) void gemm_out(const u16* __restrict__ Ao,
                                                const u16* __restrict__ Wot,
                                                float* __restrict__ out) {
  __shared__ u16 As[3 * 128 * 32];
  __shared__ u16 Bs[3 * 128 * 32];
  gemm_body(Ao, Wot, out, 0, As, Bs);
}

// ---------------- flash attention + ALiBi, no-max exp2 softmax ----------------
// grid (32 qtiles, 16 heads heavy-first, 2 batch), 256 thr = 4 waves x 16 q-rows,
// K-tile 64. Depth-2 reg-staged K/V pipeline, ALL staging state in NAMED
// ushort8 VGPRs (macros, zero runtime indexing -> no scratch). Tile t+2's
// global loads issue at top of iter t; tile t+1's ds_write goes under iter t's
// compute (compiler inserts counted vmcnt on the reg data-dep); each phase ends
// lgkmcnt(0)+s_barrier only. Q register-resident (staged once via Ps).
// Chunk swizzle c ^ (row&7) applied on the global-read side, undone at
// frag-read -> 2-way banks. ALiBi skip: tile dropped when sl2*dist > 30.
__global__ __launch_bounds__(256, 4) void flash_alibi(
    const u16* __restrict__ Qg, const u16* __restrict__ Kg,
    const u16* __restrict__ Vtg, u16* __restrict__ Og) {
  constexpr int S = 2048, Dm = 1024, HD = 64;
  __shared__ u16 Ks[2][64 * 64];   // 16 KB double-buffered
  __shared__ u16 Vs[2][64 * 64];   // 16 KB double-buffered, Vs[d][k]
  __shared__ u16 Ps[64 * 64];      // 8 KB; stages Q in prologue, then P tiles
  const int t = threadIdx.x, lane = t & 63, wid = t >> 6;  // wid 0..3
  const int quad = lane >> 4, l16 = lane & 15;
  const int qt = blockIdx.x, b = blockIdx.z;
  const int h = 15 - blockIdx.y;  // heavy heads (many k-tiles) dispatch first
  const int qBase = qt * 64;
  const size_t qRow0 = (size_t)b * S + qBase;
  const float sl2 = __builtin_amdgcn_exp2f(-0.5f * (float)(h + 1)) * 1.44269504f;
  const float sc2 = 0.125f * 1.44269504f;  // (1/sqrt(64))*log2(e)
  const int Di = (int)(30.0f / sl2);
  const int ktLo = max(0, (qBase - Di) >> 6);
  const int ktHi = min(31, (qBase + 63 + Di) >> 6);
  const int cswz = ((l16 & 7) << 3);  // frag-read chunk xor (x8 elems)
  const int pRowBase = wid * 16;      // this wave's private 16-row P region

  // per-thread staging geometry (constant across tiles); chunk0 = t, chunk1 = 256+t
  const int sr0 = t >> 3, sc0 = (((t & 7) ^ (sr0 & 7)) << 3);
  const int sr1 = 32 + sr0, sc1 = (((t & 7) ^ (sr1 & 7)) << 3);
  const u16* KgB = Kg + (size_t)b * S * Dm + h * HD;        // + (kB+row)*Dm + col
  const u16* VgB = Vtg + ((size_t)(b * 16 + h) * HD) * S;   // + row*S + kB + col

  // prologue: Q tile -> Ps via gl_lds (64 rows x 8 chunks = 512 chunks / 256 thr)
#pragma unroll
  for (int i = 0; i < 2; ++i) {
    const int ci = i * 256 + t;
    const int row = ci >> 3, col = (((ci & 7) ^ (row & 7)) << 3);
    gl_lds16(Qg + (qRow0 + row) * Dm + h * HD + col, Ps + ci * 8);
  }

  // named staging registers: two sets (A/B), each {K chunk0/1, V chunk0/1}
  ushort8 kAr0, kAr1, vAr0, vAr1, kBr0, kBr1, vBr0, vBr1;

#define FA_LOAD(kB_, kx0, kx1, vx0, vx1)                                  \
  do {                                                                    \
    kx0 = *(const ushort8*)(KgB + (size_t)((kB_) + sr0) * Dm + sc0);      \
    kx1 = *(const ushort8*)(KgB + (size_t)((kB_) + sr1) * Dm + sc1);      \
    vx0 = *(const ushort8*)(VgB + (size_t)sr0 * S + (kB_) + sc0);         \
    vx1 = *(const ushort8*)(VgB + (size_t)sr1 * S + (kB_) + sc1);         \
  } while (0)

#define FA_WRITE(Kd, Vd, kx0, kx1, vx0, vx1)                              \
  do {                                                                    \
    *(ushort8*)((Kd) + t * 8) = kx0;                                      \
    *(ushort8*)((Kd) + (256 + t) * 8) = kx1;                              \
    *(ushort8*)((Vd) + t * 8) = vx0;                                      \
    *(ushort8*)((Vd) + (256 + t) * 8) = vx1;                              \
  } while (0)

  // prologue staging: B-set <- ktLo; A-set <- ktLo+1 (if any); buf0 <- B-set.
  FA_LOAD(ktLo * 64, kBr0, kBr1, vBr0, vBr1);
  if (ktLo + 1 <= ktHi) FA_LOAD((ktLo + 1) * 64, kAr0, kAr1, vAr0, vAr1);
  FA_WRITE(Ks[0], Vs[0], kBr0, kBr1, vBr0, vBr1);
  VM0();   // once per block: Q gl_lds landed too
  LGKM0();
  BARRIER();

  // ALiBi row bias (constant over kt): bi[r] = sl2 * global_q_row
  float bi[4];
#pragma unroll
  for (int r = 0; r < 4; ++r)
    bi[r] = sl2 * (float)(qBase + wid * 16 + quad * 4 + r);

  f32x4 acc_o[4];
#pragma unroll
  for (int nd = 0; nd < 4; ++nd) acc_o[nd] = (f32x4){0.f, 0.f, 0.f, 0.f};
  float lrow[4] = {0.f, 0.f, 0.f, 0.f};

  // Q -> registers. Wave w reads only rows [16w,16w+16) of Ps == its own P
  // region; same-wave DS ordering makes these reads complete before later
  // P stores (and lgkmcnt(0) above already drained staging).
  half8 aq[2];
#pragma unroll
  for (int ks = 0; ks < 2; ++ks) {
    const int ck = ((ks * 4 + quad) << 3) ^ cswz;
    aq[ks] = *(const half8*)(Ps + (pRowBase + l16) * HD + ck);
  }

  // compute one k-tile from LDS buffers Kb/Vb (Q frags from registers)
#define FA_COMPUTE(kB_, Kb_, Vb_)                                               \
  do {                                                                          \
    f32x4 s4[4];                                                                \
    _Pragma("unroll")                                                           \
    for (int ni = 0; ni < 4; ++ni) s4[ni] = (f32x4){0.f, 0.f, 0.f, 0.f};        \
    __builtin_amdgcn_s_setprio(1);                                              \
    _Pragma("unroll")                                                           \
    for (int ks = 0; ks < 2; ++ks) {                                            \
      const int ck = ((ks * 4 + quad) << 3) ^ cswz;                             \
      _Pragma("unroll")                                                         \
      for (int ni = 0; ni < 4; ++ni) {                                          \
        const half8 bk = *(const half8*)((Kb_) + (ni * 16 + l16) * HD + ck);    \
        s4[ni] = MFMA16(aq[ks], bk, s4[ni]);                                    \
      }                                                                         \
    }                                                                           \
    __builtin_amdgcn_s_setprio(0);                                              \
    float bj[4];                                                                \
    _Pragma("unroll")                                                           \
    for (int ni = 0; ni < 4; ++ni) bj[ni] = sl2 * (float)((kB_) + ni * 16 + l16); \
    _Pragma("unroll")                                                           \
    for (int r = 0; r < 4; ++r) {                                               \
      float rs = 0.f;                                                           \
      const int prow = (pRowBase + quad * 4 + r) * 64;                          \
      _Pragma("unroll")                                                         \
      for (int ni = 0; ni < 4; ++ni) {                                          \
        const float d = fabsf(bi[r] - bj[ni]);                                  \
        const float p = __builtin_amdgcn_exp2f(s4[ni][r] * sc2 - d);            \
        rs += p;                                                                \
        Ps[prow + ((ni * 16 + l16) ^ (quad << 4))] = f2h_bits(p);               \
      }                                                                         \
      lrow[r] += rs;                                                            \
    }                                                                           \
    LGKM0(); /* wave-local: own P writes drained (P region is per-wave) */      \
    __builtin_amdgcn_s_setprio(1);                                              \
    _Pragma("unroll")                                                           \
    for (int ks = 0; ks < 2; ++ks) {                                            \
      const int pk = (ks * 32 + quad * 8) ^ ((l16 & 12) << 2);                  \
      const int ck = ((ks * 4 + quad) << 3) ^ cswz;                             \
      const half8 aP = *(const half8*)(Ps + (pRowBase + l16) * 64 + pk);        \
      _Pragma("unroll")                                                         \
      for (int nd = 0; nd < 4; ++nd) {                                          \
        const half8 bv = *(const half8*)((Vb_) + (nd * 16 + l16) * HD + ck);    \
        acc_o[nd] = MFMA16(aP, bv, acc_o[nd]);                                  \
      }                                                                         \
    }                                                                           \
    __builtin_amdgcn_s_setprio(0);                                              \
  } while (0)

  // main loop, 2x unrolled (A/B reg sets and buf0/buf1 alternate; all static).
  // FA_WRITE's ds_write depends on the reg loads -> compiler inserts a COUNTED
  // vmcnt (next tile's loads stay in flight). Reg WAR is safe: each phase's
  // LGKM0 retires the ds_writes before those regs are reloaded next phase.
  int kt = ktLo;
  for (;;) {
    // phase 0: compute kt from buf0; A-set holds kt+1; load kt+2 into B-set
    if (kt + 2 <= ktHi) FA_LOAD((kt + 2) * 64, kBr0, kBr1, vBr0, vBr1);
    if (kt + 1 <= ktHi) FA_WRITE(Ks[1], Vs[1], kAr0, kAr1, vAr0, vAr1);
    FA_COMPUTE(kt * 64, Ks[0], Vs[0]);
    LGKM0();
    BARRIER();
    if (kt + 1 > ktHi) break;
    // phase 1: compute kt+1 from buf1; B-set holds kt+2; load kt+3 into A-set
    if (kt + 3 <= ktHi) FA_LOAD((kt + 3) * 64, kAr0, kAr1, vAr0, vAr1);
    if (kt + 2 <= ktHi) FA_WRITE(Ks[0], Vs[0], kBr0, kBr1, vBr0, vBr1);
    FA_COMPUTE((kt + 1) * 64, Ks[1], Vs[1]);
    LGKM0();
    BARRIER();
    if (kt + 2 > ktHi) break;
    kt += 2;
  }
#undef FA_COMPUTE
#undef FA_LOAD
#undef FA_WRITE

  // epilogue: reduce l across the 16 lanes sharing each row, O /= l, write f16
#pragma unroll
  for (int r = 0; r < 4; ++r) {
    float l = lrow[r];
    l += __shfl_xor(l, 1);
    l += __shfl_xor(l, 2);
    l += __shfl_xor(l, 4);
    l += __shfl_xor(l, 8);
    const float inv = 1.f / l;
    const int rloc = wid * 16 + quad * 4 + r;
#pragma unroll
    for (int nd = 0; nd < 4; ++nd)
      Og[(qRow0 + rloc) * Dm + h * HD + nd * 16 + l16] = f2h_bits(acc_o[nd][r] * inv);
  }
}

extern "C" void kernel_launch(void* const* d_in, const int* in_sizes, int n_in,
                              void* d_out, int out_size, void* d_ws, size_t ws_size,
                              hipStream_t stream) {
  const float* q  = (const float*)d_in[0];
  const float* k  = (const float*)d_in[1];
  const float* v  = (const float*)d_in[2];
  const float* Wq = (const float*)d_in[3];
  const float* Wk = (const float*)d_in[4];
  const float* Wv = (const float*)d_in[5];
  const float* Wo = (const float*)d_in[6];
  char* ws = (char*)d_ws;
  const size_t MB = 1ull << 20;
  // workspace map (64 MB total)
  u16* qb  = (u16*)(ws + 0 * MB);    // 8 MB  q fp16
  u16* kb  = (u16*)(ws + 8 * MB);    // 8 MB
  u16* vb  = (u16*)(ws + 16 * MB);   // 8 MB
  u16* Wqt = (u16*)(ws + 24 * MB);   // 2 MB  W^T fp16
  u16* Wkt = (u16*)(ws + 26 * MB);
  u16* Wvt = (u16*)(ws + 28 * MB);
  u16* Wot = (u16*)(ws + 30 * MB);
  u16* Qp  = (u16*)(ws + 32 * MB);   // 8 MB  Q proj [4096][1024]
  u16* Kp  = (u16*)(ws + 40 * MB);   // 8 MB
  u16* Vtp = (u16*)(ws + 48 * MB);   // 8 MB  V proj transposed [b][h][64][2048]
  u16* Ao  = (u16*)(ws + 56 * MB);   // 8 MB  attention out [4096][1024]

  const int n = 2 * 2048 * 1024;
  cast3_h<<<dim3(n / 1024, 1, 3), 256, 0, stream>>>(q, k, v, qb, kb, vb, n);
  transpose4_h<<<dim3(32, 32, 4), 256, 0, stream>>>(Wq, Wk, Wv, Wo, Wqt, Wkt, Wvt, Wot);
  proj_qkv<<<dim3(8, 32, 3), 256, 0, stream>>>(qb, kb, vb, Wqt, Wkt, Wvt, Qp, Kp, Vtp);
  flash_alibi<<<dim3(32, 16, 2), 256, 0, stream>>>(Qp, Kp, Vtp, Ao);
  gemm_out<<<dim3(8, 32), 256, 0, stream>>>(Ao, Wot, (float*)d_out);
}

// Round 7
// 242.151 us; speedup vs baseline: 1.0875x; 1.0694x over previous
//
#include <hip/hip_runtime.h>
#include <cstdint>
#include <cstddef>

// ALiBi MHA, MI355X/gfx950. fp16 MFMA (16x16x32) pipeline.
// R11:
//  - flash: reverted EXACTLY to R6 structure (gl_lds double-buffer, one
//    __syncthreads per k-tile, Q reg-resident via Ps). R9/R10 reg-staging
//    spilled (two staging sets exceed the 128-VGPR cap at 4 blocks/CU;
//    49-55MB scratch write-back). Known-good: 51.3us, VGPR 56.
//  - GEMMs: tile M 128->64 (acc 32 VGPR, 12KB/buffer) so gemm_out grid goes
//    256 -> 512 blocks (2/CU) and proj 768 -> 1536 (4/CU resident): the
//    1-block/CU gemm_out had zero inter-block overlap to hide the per-K-step
//    barrier drain. 3-buffer counted-vmcnt(3) pipeline kept.

typedef unsigned short u16;
typedef __attribute__((ext_vector_type(8))) _Float16 half8;
typedef __attribute__((ext_vector_type(4))) float f32x4;

#define DEVI static __device__ __forceinline__
#define MFMA16(a, b, c) __builtin_amdgcn_mfma_f32_16x16x32_f16(a, b, c, 0, 0, 0)

DEVI u16 f2h_bits(float f) {
  _Float16 h = (_Float16)f;  // v_cvt_f16_f32, RNE
  union { _Float16 h; u16 u; } v; v.h = h;
  return v.u;
}

// async global->LDS, 16B per lane. LDS dest must be wave-uniform base + lane*16.
DEVI void gl_lds16(const u16* g, u16* l) {
  __builtin_amdgcn_global_load_lds(
      (const __attribute__((address_space(1))) void*)g,
      (__attribute__((address_space(3))) void*)l, 16, 0, 0);
}

#define LGKM0() __asm__ volatile("s_waitcnt lgkmcnt(0)" ::: "memory")
#define VM0()   __asm__ volatile("s_waitcnt vmcnt(0)" ::: "memory")
#define BARRIER()                       \
  do {                                  \
    __builtin_amdgcn_s_barrier();       \
    __asm__ volatile("" ::: "memory");  \
  } while (0)

// ---------------- cast fp32 -> fp16 bits, 4 elems/thread, z selects tensor ----------------
__global__ __launch_bounds__(256) void cast3_h(const float* __restrict__ in0,
                                               const float* __restrict__ in1,
                                               const float* __restrict__ in2,
                                               u16* __restrict__ o0,
                                               u16* __restrict__ o1,
                                               u16* __restrict__ o2, int n) {
  const float* in = blockIdx.z == 0 ? in0 : (blockIdx.z == 1 ? in1 : in2);
  u16* out = blockIdx.z == 0 ? o0 : (blockIdx.z == 1 ? o1 : o2);
  int i = (blockIdx.x * 256 + threadIdx.x) * 4;
  if (i + 3 < n) {
    const float4 v = *(const float4*)(in + i);
    ushort4 o;
    o.x = f2h_bits(v.x); o.y = f2h_bits(v.y); o.z = f2h_bits(v.z); o.w = f2h_bits(v.w);
    *(ushort4*)(out + i) = o;
  }
}

// ---------------- Wt[n][k] = (f16)W[k][n], 1024x1024, LDS-tiled, z selects W ----------------
__global__ __launch_bounds__(256) void transpose4_h(
    const float* __restrict__ W0, const float* __restrict__ W1,
    const float* __restrict__ W2, const float* __restrict__ W3,
    u16* __restrict__ T0, u16* __restrict__ T1, u16* __restrict__ T2,
    u16* __restrict__ T3) {
  const float* W = blockIdx.z == 0 ? W0 : (blockIdx.z == 1 ? W1 : (blockIdx.z == 2 ? W2 : W3));
  u16* Wt = blockIdx.z == 0 ? T0 : (blockIdx.z == 1 ? T1 : (blockIdx.z == 2 ? T2 : T3));
  __shared__ float tile[32][33];
  const int bx = blockIdx.x * 32;
  const int by = blockIdx.y * 32;
  const int x = threadIdx.x & 31;
  const int y0 = threadIdx.x >> 5;  // 0..7
#pragma unroll
  for (int i = y0; i < 32; i += 8)
    tile[i][x] = W[(size_t)(by + i) * 1024 + bx + x];
  __syncthreads();
#pragma unroll
  for (int i = y0; i < 32; i += 8)
    Wt[(size_t)(bx + i) * 1024 + by + x] = f2h_bits(tile[x][i]);
}

// ---------------- GEMM body: C[4096x1024] = A[4096x1024] x Bt[1024x1024]^T ----------------
// Tile 64(M) x 128(N), 4 waves side-by-side in N (each wave 64x32).
// 3-buffer depth-2 gl_lds pipeline: stage(kt+2) issued while computing kt;
// counted s_waitcnt vmcnt(3) before each barrier (3 gl_lds per stage/thread).
// 32-elem rows in LDS = 4 chunks of 8; chunk swizzle p = c ^ ((row>>1)&3).
// mode 0: fp32 out; mode 1: fp16 out row-major; mode 2: fp16 out as Vt[b][h][d][s]
DEVI void gemm_body(const u16* __restrict__ A, const u16* __restrict__ Bt,
                    void* __restrict__ Cout, int mode, u16* As, u16* Bs) {
  constexpr int K = 1024, N = 1024;
  const int t = threadIdx.x;
  const int lane = t & 63;
  const int quad = lane >> 4;
  const int l16 = lane & 15;
  const int wid = t >> 6;
  const int mBase = blockIdx.y * 64;
  const int nBase = blockIdx.x * 128;
  const int wN = wid * 32;
  const int aswz = (quad ^ ((l16 >> 1) & 3)) << 3;  // frag-read physical col

  f32x4 acc[4][2];
#pragma unroll
  for (int i = 0; i < 4; ++i)
#pragma unroll
    for (int j = 0; j < 2; ++j) acc[i][j] = (f32x4){0.f, 0.f, 0.f, 0.f};

  // staging per tile: A 64x32 (256 chunks, 1/thr) + B 128x32 (512 chunks, 2/thr)
  auto stage = [&](int kt, u16* Ad, u16* Bd) {
    {
      const int ci = t;
      const int row = ci >> 2;
      const int col = (((ci & 3) ^ ((ci >> 3) & 3)) << 3);
      gl_lds16(A + (size_t)(mBase + row) * K + kt * 32 + col, Ad + ci * 8);
    }
#pragma unroll
    for (int i = 0; i < 2; ++i) {
      const int ci = i * 256 + t;
      const int row = ci >> 2;
      const int col = (((ci & 3) ^ ((ci >> 3) & 3)) << 3);
      gl_lds16(Bt + (size_t)(nBase + row) * K + kt * 32 + col, Bd + ci * 8);
    }
  };

  u16 *a0 = As, *a1 = As + 2048, *a2 = As + 4096;
  u16 *b0 = Bs, *b1 = Bs + 4096, *b2 = Bs + 8192;

  // prologue: stage tiles 0,1; unconditional full drain (once per block)
  stage(0, a0, b0);
  stage(1, a1, b1);
  VM0();
  BARRIER();

  for (int kt = 0; kt < K / 32; ++kt) {
    if (kt + 2 < K / 32) stage(kt + 2, a2, b2);

    half8 a[4], b[2];
#pragma unroll
    for (int mi = 0; mi < 4; ++mi)
      a[mi] = *(const half8*)(a0 + (mi * 16 + l16) * 32 + aswz);
#pragma unroll
    for (int ni = 0; ni < 2; ++ni)
      b[ni] = *(const half8*)(b0 + (wN + ni * 16 + l16) * 32 + aswz);
#pragma unroll
    for (int mi = 0; mi < 4; ++mi)
#pragma unroll
      for (int ni = 0; ni < 2; ++ni)
        acc[mi][ni] = MFMA16(a[mi], b[ni], acc[mi][ni]);

    if (kt + 1 < K / 32) {
      // outstanding gl_lds: kt+1's 3 (+ kt+2's 3 if staged)
      if (kt + 2 < K / 32)
        __asm__ volatile("s_waitcnt vmcnt(3)" ::: "memory");  // kt+1 landed, kt+2 flying
      else
        VM0();  // tail: last tile landed
      __builtin_amdgcn_sched_barrier(0);
      LGKM0();  // own frag ds_reads done -> safe for others to overwrite old buf
      BARRIER();
    }
    u16* ta = a0; a0 = a1; a1 = a2; a2 = ta;
    u16* tb = b0; b0 = b1; b1 = b2; b2 = tb;
  }

  // epilogue. C/D layout: row = quad*4 + reg, col = lane&15 (m89/m91-verified)
#pragma unroll
  for (int mi = 0; mi < 4; ++mi) {
#pragma unroll
    for (int ni = 0; ni < 2; ++ni) {
#pragma unroll
      for (int r = 0; r < 4; ++r) {
        const int m = mBase + mi * 16 + quad * 4 + r;
        const int n = nBase + wN + ni * 16 + l16;
        const float v = acc[mi][ni][r];
        if (mode == 0) {
          ((float*)Cout)[(size_t)m * N + n] = v;
        } else if (mode == 1) {
          ((u16*)Cout)[(size_t)m * N + n] = f2h_bits(v);
        } else {
          // Vt[(b*1024 + n)][s], b = m>>11, s = m&2047, S=2048
          ((u16*)Cout)[(((size_t)(m >> 11) * 1024 + n) << 11) | (size_t)(m & 2047)] = f2h_bits(v);
        }
      }
    }
  }
}

__global__ __launch_bounds__(256, 4) void proj_qkv(
    const u16* __restrict__ qb, const u16* __restrict__ kb, const u16* __restrict__ vb,
    const u16* __restrict__ Wqt, const u16* __restrict__ Wkt, const u16* __restrict__ Wvt,
    u16* __restrict__ Qp, u16* __restrict__ Kp, u16* __restrict__ Vtp) {
  __shared__ u16 As[3 * 64 * 32];   // 12 KB (3 buffers)
  __shared__ u16 Bs[3 * 128 * 32];  // 24 KB
  const int z = blockIdx.z;
  const u16* A = z == 0 ? qb : (z == 1 ? kb : vb);
  const u16* Bt = z == 0 ? Wqt : (z == 1 ? Wkt : Wvt);
  void* C = z == 0 ? (void*)Qp : (z == 1 ? (void*)Kp : (void*)Vtp);
  gemm_body(A, Bt, C, z == 2 ? 2 : 1, As, Bs);
}

__global__ __launch_bounds__(256, 4) void gemm_out(const u16* __restrict__ Ao,
                                                   const u16* __restrict__ Wot,
                                                   float* __restrict__ out) {
  __shared__ u16 As[3 * 64 * 32];
  __shared__ u16 Bs[3 * 128 * 32];
  gemm_body(Ao, Wot, out, 0, As, Bs);
}

// ---------------- flash attention + ALiBi, no-max exp2 softmax ----------------
// grid (32 qtiles, 16 heads heavy-first, 2 batch), 256 thr = 4 waves x 16 q-rows,
// K-tile 64, double-buffered K/V, stage-early pipeline w/ ONE barrier per tile.
// Q is register-resident (staged once via the Ps buffer; wave-private rows).
// Ks/Vs rows are 64 f16 = 8 chunks; chunk swizzle p = c ^ (row&7) applied on
// the global side of the staging load, undone at frag-read time -> 2-way banks.
// ALiBi skip: tile dropped when sl2*dist > 30 (neglected mass < 2^-15 of l).
__global__ __launch_bounds__(256, 4) void flash_alibi(
    const u16* __restrict__ Qg, const u16* __restrict__ Kg,
    const u16* __restrict__ Vtg, u16* __restrict__ Og) {
  constexpr int S = 2048, Dm = 1024, HD = 64;
  __shared__ u16 Ks[2][64 * 64];   // 16 KB double-buffered
  __shared__ u16 Vs[2][64 * 64];   // 16 KB double-buffered, Vs[d][k]
  __shared__ u16 Ps[64 * 64];      // 8 KB; stages Q in prologue, then P tiles
  const int t = threadIdx.x, lane = t & 63, wid = t >> 6;  // wid 0..3
  const int quad = lane >> 4, l16 = lane & 15;
  const int qt = blockIdx.x, b = blockIdx.z;
  const int h = 15 - blockIdx.y;  // heavy heads (many k-tiles) dispatch first
  const int qBase = qt * 64;
  const size_t qRow0 = (size_t)b * S + qBase;
  const float sl2 = __builtin_amdgcn_exp2f(-0.5f * (float)(h + 1)) * 1.44269504f;
  const float sc2 = 0.125f * 1.44269504f;  // (1/sqrt(64))*log2(e)
  const int Di = (int)(30.0f / sl2);
  const int ktLo = max(0, (qBase - Di) >> 6);
  const int ktHi = min(31, (qBase + 63 + Di) >> 6);
  const int cswz = ((l16 & 7) << 3);  // frag-read chunk xor (x8 elems)
  const int pRowBase = wid * 16;      // this wave's private 16-row P region

  // prologue staging: Q tile -> Ps (64 rows x 8 chunks = 512 chunks / 256 thr)
#pragma unroll
  for (int i = 0; i < 2; ++i) {
    const int ci = i * 256 + t;
    const int row = ci >> 3, col = (((ci & 7) ^ (row & 7)) << 3);
    gl_lds16(Qg + (qRow0 + row) * Dm + h * HD + col, Ps + ci * 8);
  }
  // prologue staging: K/V tile ktLo into buffer 0
  {
    const int kB = ktLo * 64;
#pragma unroll
    for (int i = 0; i < 2; ++i) {
      const int ci = i * 256 + t;
      const int row = ci >> 3, col = (((ci & 7) ^ (row & 7)) << 3);
      gl_lds16(Kg + ((size_t)b * S + kB + row) * Dm + h * HD + col, Ks[0] + ci * 8);
      gl_lds16(Vtg + ((size_t)(b * 16 + h) * HD + row) * S + kB + col, Vs[0] + ci * 8);
    }
  }

  // ALiBi row bias (constant over kt): bi[r] = sl2 * global_q_row
  float bi[4];
#pragma unroll
  for (int r = 0; r < 4; ++r)
    bi[r] = sl2 * (float)(qBase + wid * 16 + quad * 4 + r);

  f32x4 acc_o[4];
#pragma unroll
  for (int nd = 0; nd < 4; ++nd) acc_o[nd] = (f32x4){0.f, 0.f, 0.f, 0.f};
  float lrow[4] = {0.f, 0.f, 0.f, 0.f};

  __syncthreads();  // drains vmcnt: Q + first K/V tile resident

  // Q -> registers. Wave w reads only rows [16w, 16w+16) of Ps == its own P
  // region, so no cross-wave hazard with later P writes; DS ops are wave-ordered
  // so these reads complete before this wave's own softmax stores below.
  half8 aq[2];
#pragma unroll
  for (int ks = 0; ks < 2; ++ks) {
    const int ck = ((ks * 4 + quad) << 3) ^ cswz;
    aq[ks] = *(const half8*)(Ps + (pRowBase + l16) * HD + ck);
  }

  int bb = 0;
  for (int kt = ktLo; kt <= ktHi; ++kt) {
    const int kB = kt * 64;
    // stage NEXT tile into the other buffer, latency hidden under this tile's compute
    if (kt < ktHi) {
      const int kBn = kB + 64;
#pragma unroll
      for (int i = 0; i < 2; ++i) {
        const int ci = i * 256 + t;
        const int row = ci >> 3, col = (((ci & 7) ^ (row & 7)) << 3);
        gl_lds16(Kg + ((size_t)b * S + kBn + row) * Dm + h * HD + col, Ks[bb ^ 1] + ci * 8);
        gl_lds16(Vtg + ((size_t)(b * 16 + h) * HD + row) * S + kBn + col, Vs[bb ^ 1] + ci * 8);
      }
    }

    const u16* Kb = Ks[bb];
    const u16* Vb = Vs[bb];

    // S = Q K^T : per wave 16q x 64k  (Q frags from registers)
    f32x4 s4[4];
#pragma unroll
    for (int ni = 0; ni < 4; ++ni) s4[ni] = (f32x4){0.f, 0.f, 0.f, 0.f};
    __builtin_amdgcn_s_setprio(1);
#pragma unroll
    for (int ks = 0; ks < 2; ++ks) {
      const int ck = ((ks * 4 + quad) << 3) ^ cswz;
#pragma unroll
      for (int ni = 0; ni < 4; ++ni) {
        const half8 bk = *(const half8*)(Kb + (ni * 16 + l16) * HD + ck);
        s4[ni] = MFMA16(aq[ks], bk, s4[ni]);
      }
    }
    __builtin_amdgcn_s_setprio(0);

    // p = exp2(s*sc2 - |bi - bj|); per-lane l partials; write swizzled P
    float bj[4];
#pragma unroll
    for (int ni = 0; ni < 4; ++ni) bj[ni] = sl2 * (float)(kB + ni * 16 + l16);
#pragma unroll
    for (int r = 0; r < 4; ++r) {
      float rs = 0.f;
      const int prow = (pRowBase + quad * 4 + r) * 64;
#pragma unroll
      for (int ni = 0; ni < 4; ++ni) {
        const float d = fabsf(bi[r] - bj[ni]);
        const float p = __builtin_amdgcn_exp2f(s4[ni][r] * sc2 - d);
        rs += p;
        Ps[prow + ((ni * 16 + l16) ^ (quad << 4))] = f2h_bits(p);
      }
      lrow[r] += rs;
    }
    // P region is per-wave: wave-local LDS drain is sufficient (no block barrier)
    __asm__ volatile("s_waitcnt lgkmcnt(0)" ::: "memory");

    // O += P V : P A-frags (swizzled, 16B-contiguous), V B-frags
    __builtin_amdgcn_s_setprio(1);
#pragma unroll
    for (int ks = 0; ks < 2; ++ks) {
      const int pk = (ks * 32 + quad * 8) ^ ((l16 & 12) << 2);
      const int ck = ((ks * 4 + quad) << 3) ^ cswz;
      const half8 aP = *(const half8*)(Ps + (pRowBase + l16) * 64 + pk);
#pragma unroll
      for (int nd = 0; nd < 4; ++nd) {
        const half8 bv = *(const half8*)(Vb + (nd * 16 + l16) * HD + ck);
        acc_o[nd] = MFMA16(aP, bv, acc_o[nd]);
      }
    }
    __builtin_amdgcn_s_setprio(0);

    __syncthreads();  // ONE barrier/iter: drains next-tile stage (vmcnt) + all LDS reads
    bb ^= 1;
  }

  // epilogue: reduce l across the 16 lanes sharing each row, O /= l, write f16
#pragma unroll
  for (int r = 0; r < 4; ++r) {
    float l = lrow[r];
    l += __shfl_xor(l, 1);
    l += __shfl_xor(l, 2);
    l += __shfl_xor(l, 4);
    l += __shfl_xor(l, 8);
    const float inv = 1.f / l;
    const int rloc = wid * 16 + quad * 4 + r;
#pragma unroll
    for (int nd = 0; nd < 4; ++nd)
      Og[(qRow0 + rloc) * Dm + h * HD + nd * 16 + l16] = f2h_bits(acc_o[nd][r] * inv);
  }
}

extern "C" void kernel_launch(void* const* d_in, const int* in_sizes, int n_in,
                              void* d_out, int out_size, void* d_ws, size_t ws_size,
                              hipStream_t stream) {
  const float* q  = (const float*)d_in[0];
  const float* k  = (const float*)d_in[1];
  const float* v  = (const float*)d_in[2];
  const float* Wq = (const float*)d_in[3];
  const float* Wk = (const float*)d_in[4];
  const float* Wv = (const float*)d_in[5];
  const float* Wo = (const float*)d_in[6];
  char* ws = (char*)d_ws;
  const size_t MB = 1ull << 20;
  // workspace map (64 MB total)
  u16* qb  = (u16*)(ws + 0 * MB);    // 8 MB  q fp16
  u16* kb  = (u16*)(ws + 8 * MB);    // 8 MB
  u16* vb  = (u16*)(ws + 16 * MB);   // 8 MB
  u16* Wqt = (u16*)(ws + 24 * MB);   // 2 MB  W^T fp16
  u16* Wkt = (u16*)(ws + 26 * MB);
  u16* Wvt = (u16*)(ws + 28 * MB);
  u16* Wot = (u16*)(ws + 30 * MB);
  u16* Qp  = (u16*)(ws + 32 * MB);   // 8 MB  Q proj [4096][1024]
  u16* Kp  = (u16*)(ws + 40 * MB);   // 8 MB
  u16* Vtp = (u16*)(ws + 48 * MB);   // 8 MB  V proj transposed [b][h][64][2048]
  u16* Ao  = (u16*)(ws + 56 * MB);   // 8 MB  attention out [4096][1024]

  const int n = 2 * 2048 * 1024;
  cast3_h<<<dim3(n / 1024, 1, 3), 256, 0, stream>>>(q, k, v, qb, kb, vb, n);
  transpose4_h<<<dim3(32, 32, 4), 256, 0, stream>>>(Wq, Wk, Wv, Wo, Wqt, Wkt, Wvt, Wot);
  proj_qkv<<<dim3(8, 64, 3), 256, 0, stream>>>(qb, kb, vb, Wqt, Wkt, Wvt, Qp, Kp, Vtp);
  flash_alibi<<<dim3(32, 16, 2), 256, 0, stream>>>(Qp, Kp, Vtp, Ao);
  gemm_out<<<dim3(8, 64), 256, 0, stream>>>(Ao, Wot, (float*)d_out);
}

// Round 8
// 223.074 us; speedup vs baseline: 1.1805x; 1.0855x over previous
//
#include <hip/hip_runtime.h>
#include <cstdint>
#include <cstddef>

// ALiBi MHA, MI355X/gfx950. fp16 MFMA (16x16x32) pipeline.
// R12:
//  - GEMMs: back to 128x128 tile (R11's M=64 halved per-block arithmetic
//    intensity and regressed proj 51->71us), 3-buffer counted-vmcnt(4)
//    pipeline (R9's, measured neutral), PLUS bijective chunked XCD swizzle:
//    unswizzled, XCD = bx (each A-panel fetched by 8 different XCDs -> 8x
//    over-fetch; proj FETCH=101MB vs ~30MB ideal). Swizzled, XCD x hosts
//    by' in {4x..4x+3} x all bx: per-XCD/z set = 1MB A + 2MB W < 4MB L2.
//  - flash: unchanged from R11 (R6 structure; known ~51us).

typedef unsigned short u16;
typedef __attribute__((ext_vector_type(8))) _Float16 half8;
typedef __attribute__((ext_vector_type(4))) float f32x4;

#define DEVI static __device__ __forceinline__
#define MFMA16(a, b, c) __builtin_amdgcn_mfma_f32_16x16x32_f16(a, b, c, 0, 0, 0)

DEVI u16 f2h_bits(float f) {
  _Float16 h = (_Float16)f;  // v_cvt_f16_f32, RNE
  union { _Float16 h; u16 u; } v; v.h = h;
  return v.u;
}

// async global->LDS, 16B per lane. LDS dest must be wave-uniform base + lane*16.
DEVI void gl_lds16(const u16* g, u16* l) {
  __builtin_amdgcn_global_load_lds(
      (const __attribute__((address_space(1))) void*)g,
      (__attribute__((address_space(3))) void*)l, 16, 0, 0);
}

#define LGKM0() __asm__ volatile("s_waitcnt lgkmcnt(0)" ::: "memory")
#define VM0()   __asm__ volatile("s_waitcnt vmcnt(0)" ::: "memory")
#define BARRIER()                       \
  do {                                  \
    __builtin_amdgcn_s_barrier();       \
    __asm__ volatile("" ::: "memory");  \
  } while (0)

// ---------------- cast fp32 -> fp16 bits, 4 elems/thread, z selects tensor ----------------
__global__ __launch_bounds__(256) void cast3_h(const float* __restrict__ in0,
                                               const float* __restrict__ in1,
                                               const float* __restrict__ in2,
                                               u16* __restrict__ o0,
                                               u16* __restrict__ o1,
                                               u16* __restrict__ o2, int n) {
  const float* in = blockIdx.z == 0 ? in0 : (blockIdx.z == 1 ? in1 : in2);
  u16* out = blockIdx.z == 0 ? o0 : (blockIdx.z == 1 ? o1 : o2);
  int i = (blockIdx.x * 256 + threadIdx.x) * 4;
  if (i + 3 < n) {
    const float4 v = *(const float4*)(in + i);
    ushort4 o;
    o.x = f2h_bits(v.x); o.y = f2h_bits(v.y); o.z = f2h_bits(v.z); o.w = f2h_bits(v.w);
    *(ushort4*)(out + i) = o;
  }
}

// ---------------- Wt[n][k] = (f16)W[k][n], 1024x1024, LDS-tiled, z selects W ----------------
__global__ __launch_bounds__(256) void transpose4_h(
    const float* __restrict__ W0, const float* __restrict__ W1,
    const float* __restrict__ W2, const float* __restrict__ W3,
    u16* __restrict__ T0, u16* __restrict__ T1, u16* __restrict__ T2,
    u16* __restrict__ T3) {
  const float* W = blockIdx.z == 0 ? W0 : (blockIdx.z == 1 ? W1 : (blockIdx.z == 2 ? W2 : W3));
  u16* Wt = blockIdx.z == 0 ? T0 : (blockIdx.z == 1 ? T1 : (blockIdx.z == 2 ? T2 : T3));
  __shared__ float tile[32][33];
  const int bx = blockIdx.x * 32;
  const int by = blockIdx.y * 32;
  const int x = threadIdx.x & 31;
  const int y0 = threadIdx.x >> 5;  // 0..7
#pragma unroll
  for (int i = y0; i < 32; i += 8)
    tile[i][x] = W[(size_t)(by + i) * 1024 + bx + x];
  __syncthreads();
#pragma unroll
  for (int i = y0; i < 32; i += 8)
    Wt[(size_t)(bx + i) * 1024 + by + x] = f2h_bits(tile[x][i]);
}

// ---------------- GEMM body: C[4096x1024] = A[4096x1024] x Bt[1024x1024]^T ----------------
// Tile 128x128, 2x2 waves. Grid per z is (8, 32); XCD-chunked bijective swizzle
// (nwg=256 % 8 == 0): hw g2 -> L = (g2&7)*32 + (g2>>3); by'=L/8, bx'=L%8.
// 3-buffer depth-2 gl_lds pipeline: stage(kt+2) issued while computing kt;
// counted s_waitcnt vmcnt(4) (never 0 mid-loop) + raw barriers.
// 32-elem rows in LDS = 4 chunks of 8; chunk swizzle p = c ^ ((row>>1)&3).
// mode 0: fp32 out; mode 1: fp16 out row-major; mode 2: fp16 out as Vt[b][h][d][s]
DEVI void gemm_body(const u16* __restrict__ A, const u16* __restrict__ Bt,
                    void* __restrict__ Cout, int mode, u16* As, u16* Bs) {
  constexpr int K = 1024, N = 1024;
  const int t = threadIdx.x;
  const int lane = t & 63;
  const int quad = lane >> 4;
  const int l16 = lane & 15;
  const int wid = t >> 6;
  // XCD-chunked swizzle: XCD x hosts output rows by' = 4x..4x+3 (all bx)
  const int g2 = blockIdx.y * 8 + blockIdx.x;
  const int L = (g2 & 7) * 32 + (g2 >> 3);
  const int mBase = (L >> 3) * 128;
  const int nBase = (L & 7) * 128;
  const int wM = (wid >> 1) * 64;
  const int wN = (wid & 1) * 64;
  const int aswz = (quad ^ ((l16 >> 1) & 3)) << 3;  // frag-read physical col

  f32x4 acc[4][4];
#pragma unroll
  for (int i = 0; i < 4; ++i)
#pragma unroll
    for (int j = 0; j < 4; ++j) acc[i][j] = (f32x4){0.f, 0.f, 0.f, 0.f};

  // staging: 128x32 f16 tile = 8KB = 512 16B-chunks / 256 thr, A and B each
  auto stage = [&](int kt, u16* Ad, u16* Bd) {
#pragma unroll
    for (int i = 0; i < 2; ++i) {
      const int ci = i * 256 + t;
      const int row = ci >> 2;                              // 4 chunks per 32-elem row
      const int col = (((ci & 3) ^ ((ci >> 3) & 3)) << 3);  // staging-side swizzle
      gl_lds16(A + (size_t)(mBase + row) * K + kt * 32 + col, Ad + ci * 8);
      gl_lds16(Bt + (size_t)(nBase + row) * K + kt * 32 + col, Bd + ci * 8);
    }
  };

  u16 *a0 = As, *a1 = As + 4096, *a2 = As + 8192;
  u16 *b0 = Bs, *b1 = Bs + 4096, *b2 = Bs + 8192;

  // prologue: stage tiles 0,1; unconditional full drain (once per block)
  stage(0, a0, b0);
  stage(1, a1, b1);
  VM0();
  BARRIER();

  for (int kt = 0; kt < K / 32; ++kt) {
    if (kt + 2 < K / 32) stage(kt + 2, a2, b2);

    half8 a[4], b[4];
#pragma unroll
    for (int mi = 0; mi < 4; ++mi)
      a[mi] = *(const half8*)(a0 + (wM + mi * 16 + l16) * 32 + aswz);
#pragma unroll
    for (int ni = 0; ni < 4; ++ni)
      b[ni] = *(const half8*)(b0 + (wN + ni * 16 + l16) * 32 + aswz);
#pragma unroll
    for (int mi = 0; mi < 4; ++mi)
#pragma unroll
      for (int ni = 0; ni < 4; ++ni)
        acc[mi][ni] = MFMA16(a[mi], b[ni], acc[mi][ni]);

    if (kt + 1 < K / 32) {
      // outstanding gl_lds here: kt+1's 4 (+ kt+2's 4 if staged).
      if (kt + 2 < K / 32)
        __asm__ volatile("s_waitcnt vmcnt(4)" ::: "memory");  // kt+1 landed, kt+2 flying
      else
        VM0();  // tail: last tile landed
      __builtin_amdgcn_sched_barrier(0);
      LGKM0();  // own frag ds_reads done -> safe for others to overwrite old buf
      BARRIER();
    }
    u16* ta = a0; a0 = a1; a1 = a2; a2 = ta;
    u16* tb = b0; b0 = b1; b1 = b2; b2 = tb;
  }

  // epilogue. C/D layout: row = quad*4 + reg, col = lane&15 (m89/m91-verified)
#pragma unroll
  for (int mi = 0; mi < 4; ++mi) {
#pragma unroll
    for (int ni = 0; ni < 4; ++ni) {
#pragma unroll
      for (int r = 0; r < 4; ++r) {
        const int m = mBase + wM + mi * 16 + quad * 4 + r;
        const int n = nBase + wN + ni * 16 + l16;
        const float v = acc[mi][ni][r];
        if (mode == 0) {
          ((float*)Cout)[(size_t)m * N + n] = v;
        } else if (mode == 1) {
          ((u16*)Cout)[(size_t)m * N + n] = f2h_bits(v);
        } else {
          // Vt[(b*1024 + n)][s], b = m>>11, s = m&2047, S=2048
          ((u16*)Cout)[(((size_t)(m >> 11) * 1024 + n) << 11) | (size_t)(m & 2047)] = f2h_bits(v);
        }
      }
    }
  }
}

__global__ __launch_bounds__(256) void proj_qkv(
    const u16* __restrict__ qb, const u16* __restrict__ kb, const u16* __restrict__ vb,
    const u16* __restrict__ Wqt, const u16* __restrict__ Wkt, const u16* __restrict__ Wvt,
    u16* __restrict__ Qp, u16* __restrict__ Kp, u16* __restrict__ Vtp) {
  __shared__ u16 As[3 * 128 * 32];  // 24 KB (3 buffers)
  __shared__ u16 Bs[3 * 128 * 32];  // 24 KB
  const int z = blockIdx.z;
  const u16* A = z == 0 ? qb : (z == 1 ? kb : vb);
  const u16* Bt = z == 0 ? Wqt : (z == 1 ? Wkt : Wvt);
  void* C = z == 0 ? (void*)Qp : (z == 1 ? (void*)Kp : (void*)Vtp);
  gemm_body(A, Bt, C, z == 2 ? 2 : 1, As, Bs);
}

__global__ __launch_bounds__(256) void gemm_out(const u16* __restrict__ Ao,
                                                const u16* __restrict__ Wot,
                                                float* __restrict__ out) {
  __shared__ u16 As[3 * 128 * 32];
  __shared__ u16 Bs[3 * 128 * 32];
  gemm_body(Ao, Wot, out, 0, As, Bs);
}

// ---------------- flash attention + ALiBi, no-max exp2 softmax ----------------
// grid (32 qtiles, 16 heads heavy-first, 2 batch), 256 thr = 4 waves x 16 q-rows,
// K-tile 64, double-buffered K/V, stage-early pipeline w/ ONE barrier per tile.
// Q is register-resident (staged once via the Ps buffer; wave-private rows).
// Ks/Vs rows are 64 f16 = 8 chunks; chunk swizzle p = c ^ (row&7) applied on
// the global side of the staging load, undone at frag-read time -> 2-way banks.
// ALiBi skip: tile dropped when sl2*dist > 30 (neglected mass < 2^-15 of l).
__global__ __launch_bounds__(256, 4) void flash_alibi(
    const u16* __restrict__ Qg, const u16* __restrict__ Kg,
    const u16* __restrict__ Vtg, u16* __restrict__ Og) {
  constexpr int S = 2048, Dm = 1024, HD = 64;
  __shared__ u16 Ks[2][64 * 64];   // 16 KB double-buffered
  __shared__ u16 Vs[2][64 * 64];   // 16 KB double-buffered, Vs[d][k]
  __shared__ u16 Ps[64 * 64];      // 8 KB; stages Q in prologue, then P tiles
  const int t = threadIdx.x, lane = t & 63, wid = t >> 6;  // wid 0..3
  const int quad = lane >> 4, l16 = lane & 15;
  const int qt = blockIdx.x, b = blockIdx.z;
  const int h = 15 - blockIdx.y;  // heavy heads (many k-tiles) dispatch first
  const int qBase = qt * 64;
  const size_t qRow0 = (size_t)b * S + qBase;
  const float sl2 = __builtin_amdgcn_exp2f(-0.5f * (float)(h + 1)) * 1.44269504f;
  const float sc2 = 0.125f * 1.44269504f;  // (1/sqrt(64))*log2(e)
  const int Di = (int)(30.0f / sl2);
  const int ktLo = max(0, (qBase - Di) >> 6);
  const int ktHi = min(31, (qBase + 63 + Di) >> 6);
  const int cswz = ((l16 & 7) << 3);  // frag-read chunk xor (x8 elems)
  const int pRowBase = wid * 16;      // this wave's private 16-row P region

  // prologue staging: Q tile -> Ps (64 rows x 8 chunks = 512 chunks / 256 thr)
#pragma unroll
  for (int i = 0; i < 2; ++i) {
    const int ci = i * 256 + t;
    const int row = ci >> 3, col = (((ci & 7) ^ (row & 7)) << 3);
    gl_lds16(Qg + (qRow0 + row) * Dm + h * HD + col, Ps + ci * 8);
  }
  // prologue staging: K/V tile ktLo into buffer 0
  {
    const int kB = ktLo * 64;
#pragma unroll
    for (int i = 0; i < 2; ++i) {
      const int ci = i * 256 + t;
      const int row = ci >> 3, col = (((ci & 7) ^ (row & 7)) << 3);
      gl_lds16(Kg + ((size_t)b * S + kB + row) * Dm + h * HD + col, Ks[0] + ci * 8);
      gl_lds16(Vtg + ((size_t)(b * 16 + h) * HD + row) * S + kB + col, Vs[0] + ci * 8);
    }
  }

  // ALiBi row bias (constant over kt): bi[r] = sl2 * global_q_row
  float bi[4];
#pragma unroll
  for (int r = 0; r < 4; ++r)
    bi[r] = sl2 * (float)(qBase + wid * 16 + quad * 4 + r);

  f32x4 acc_o[4];
#pragma unroll
  for (int nd = 0; nd < 4; ++nd) acc_o[nd] = (f32x4){0.f, 0.f, 0.f, 0.f};
  float lrow[4] = {0.f, 0.f, 0.f, 0.f};

  __syncthreads();  // drains vmcnt: Q + first K/V tile resident

  // Q -> registers. Wave w reads only rows [16w, 16w+16) of Ps == its own P
  // region, so no cross-wave hazard with later P writes; DS ops are wave-ordered
  // so these reads complete before this wave's own softmax stores below.
  half8 aq[2];
#pragma unroll
  for (int ks = 0; ks < 2; ++ks) {
    const int ck = ((ks * 4 + quad) << 3) ^ cswz;
    aq[ks] = *(const half8*)(Ps + (pRowBase + l16) * HD + ck);
  }

  int bb = 0;
  for (int kt = ktLo; kt <= ktHi; ++kt) {
    const int kB = kt * 64;
    // stage NEXT tile into the other buffer, latency hidden under this tile's compute
    if (kt < ktHi) {
      const int kBn = kB + 64;
#pragma unroll
      for (int i = 0; i < 2; ++i) {
        const int ci = i * 256 + t;
        const int row = ci >> 3, col = (((ci & 7) ^ (row & 7)) << 3);
        gl_lds16(Kg + ((size_t)b * S + kBn + row) * Dm + h * HD + col, Ks[bb ^ 1] + ci * 8);
        gl_lds16(Vtg + ((size_t)(b * 16 + h) * HD + row) * S + kBn + col, Vs[bb ^ 1] + ci * 8);
      }
    }

    const u16* Kb = Ks[bb];
    const u16* Vb = Vs[bb];

    // S = Q K^T : per wave 16q x 64k  (Q frags from registers)
    f32x4 s4[4];
#pragma unroll
    for (int ni = 0; ni < 4; ++ni) s4[ni] = (f32x4){0.f, 0.f, 0.f, 0.f};
    __builtin_amdgcn_s_setprio(1);
#pragma unroll
    for (int ks = 0; ks < 2; ++ks) {
      const int ck = ((ks * 4 + quad) << 3) ^ cswz;
#pragma unroll
      for (int ni = 0; ni < 4; ++ni) {
        const half8 bk = *(const half8*)(Kb + (ni * 16 + l16) * HD + ck);
        s4[ni] = MFMA16(aq[ks], bk, s4[ni]);
      }
    }
    __builtin_amdgcn_s_setprio(0);

    // p = exp2(s*sc2 - |bi - bj|); per-lane l partials; write swizzled P
    float bj[4];
#pragma unroll
    for (int ni = 0; ni < 4; ++ni) bj[ni] = sl2 * (float)(kB + ni * 16 + l16);
#pragma unroll
    for (int r = 0; r < 4; ++r) {
      float rs = 0.f;
      const int prow = (pRowBase + quad * 4 + r) * 64;
#pragma unroll
      for (int ni = 0; ni < 4; ++ni) {
        const float d = fabsf(bi[r] - bj[ni]);
        const float p = __builtin_amdgcn_exp2f(s4[ni][r] * sc2 - d);
        rs += p;
        Ps[prow + ((ni * 16 + l16) ^ (quad << 4))] = f2h_bits(p);
      }
      lrow[r] += rs;
    }
    // P region is per-wave: wave-local LDS drain is sufficient (no block barrier)
    __asm__ volatile("s_waitcnt lgkmcnt(0)" ::: "memory");

    // O += P V : P A-frags (swizzled, 16B-contiguous), V B-frags
    __builtin_amdgcn_s_setprio(1);
#pragma unroll
    for (int ks = 0; ks < 2; ++ks) {
      const int pk = (ks * 32 + quad * 8) ^ ((l16 & 12) << 2);
      const int ck = ((ks * 4 + quad) << 3) ^ cswz;
      const half8 aP = *(const half8*)(Ps + (pRowBase + l16) * 64 + pk);
#pragma unroll
      for (int nd = 0; nd < 4; ++nd) {
        const half8 bv = *(const half8*)(Vb + (nd * 16 + l16) * HD + ck);
        acc_o[nd] = MFMA16(aP, bv, acc_o[nd]);
      }
    }
    __builtin_amdgcn_s_setprio(0);

    __syncthreads();  // ONE barrier/iter: drains next-tile stage (vmcnt) + all LDS reads
    bb ^= 1;
  }

  // epilogue: reduce l across the 16 lanes sharing each row, O /= l, write f16
#pragma unroll
  for (int r = 0; r < 4; ++r) {
    float l = lrow[r];
    l += __shfl_xor(l, 1);
    l += __shfl_xor(l, 2);
    l += __shfl_xor(l, 4);
    l += __shfl_xor(l, 8);
    const float inv = 1.f / l;
    const int rloc = wid * 16 + quad * 4 + r;
#pragma unroll
    for (int nd = 0; nd < 4; ++nd)
      Og[(qRow0 + rloc) * Dm + h * HD + nd * 16 + l16] = f2h_bits(acc_o[nd][r] * inv);
  }
}

extern "C" void kernel_launch(void* const* d_in, const int* in_sizes, int n_in,
                              void* d_out, int out_size, void* d_ws, size_t ws_size,
                              hipStream_t stream) {
  const float* q  = (const float*)d_in[0];
  const float* k  = (const float*)d_in[1];
  const float* v  = (const float*)d_in[2];
  const float* Wq = (const float*)d_in[3];
  const float* Wk = (const float*)d_in[4];
  const float* Wv = (const float*)d_in[5];
  const float* Wo = (const float*)d_in[6];
  char* ws = (char*)d_ws;
  const size_t MB = 1ull << 20;
  // workspace map (64 MB total)
  u16* qb  = (u16*)(ws + 0 * MB);    // 8 MB  q fp16
  u16* kb  = (u16*)(ws + 8 * MB);    // 8 MB
  u16* vb  = (u16*)(ws + 16 * MB);   // 8 MB
  u16* Wqt = (u16*)(ws + 24 * MB);   // 2 MB  W^T fp16
  u16* Wkt = (u16*)(ws + 26 * MB);
  u16* Wvt = (u16*)(ws + 28 * MB);
  u16* Wot = (u16*)(ws + 30 * MB);
  u16* Qp  = (u16*)(ws + 32 * MB);   // 8 MB  Q proj [4096][1024]
  u16* Kp  = (u16*)(ws + 40 * MB);   // 8 MB
  u16* Vtp = (u16*)(ws + 48 * MB);   // 8 MB  V proj transposed [b][h][64][2048]
  u16* Ao  = (u16*)(ws + 56 * MB);   // 8 MB  attention out [4096][1024]

  const int n = 2 * 2048 * 1024;
  cast3_h<<<dim3(n / 1024, 1, 3), 256, 0, stream>>>(q, k, v, qb, kb, vb, n);
  transpose4_h<<<dim3(32, 32, 4), 256, 0, stream>>>(Wq, Wk, Wv, Wo, Wqt, Wkt, Wvt, Wot);
  proj_qkv<<<dim3(8, 32, 3), 256, 0, stream>>>(qb, kb, vb, Wqt, Wkt, Wvt, Qp, Kp, Vtp);
  flash_alibi<<<dim3(32, 16, 2), 256, 0, stream>>>(Qp, Kp, Vtp, Ao);
  gemm_out<<<dim3(8, 32), 256, 0, stream>>>(Ao, Wot, (float*)d_out);
}

// Round 9
// 219.515 us; speedup vs baseline: 1.1997x; 1.0162x over previous
//
#include <hip/hip_runtime.h>
#include <cstdint>
#include <cstddef>

// ALiBi MHA, MI355X/gfx950. fp16 MFMA (16x16x32) pipeline.
// R13 changes vs R12:
//  - flash: head pairing remap h = (y<8 ? 15-y : y-8). With 1024 blocks =
//    exactly 4/CU, co-resident blocks are ids {i,i+256,i+512,i+768} =
//    head-pair (f(y),f(y+8)) twice. Old map paired (15,7)..(8,0): per-CU
//    38..86 k-tiles (86 sets the makespan). New map pairs heavy+light:
//    (15,0),(14,1).. -> 54..70 tiles/CU.
//  - cast3_h + transpose4_h fused into ONE prep kernel (z 0-2 cast, 3-6
//    transpose): one fewer launch (~10us gap each, ~55us total gaps measured
//    as sum-of-kernels 165us vs 223us wall).
//  - GEMMs unchanged from R12 (128x128, 3-buffer vmcnt(4), XCD swizzle).

typedef unsigned short u16;
typedef __attribute__((ext_vector_type(8))) _Float16 half8;
typedef __attribute__((ext_vector_type(4))) float f32x4;

#define DEVI static __device__ __forceinline__
#define MFMA16(a, b, c) __builtin_amdgcn_mfma_f32_16x16x32_f16(a, b, c, 0, 0, 0)

DEVI u16 f2h_bits(float f) {
  _Float16 h = (_Float16)f;  // v_cvt_f16_f32, RNE
  union { _Float16 h; u16 u; } v; v.h = h;
  return v.u;
}

// async global->LDS, 16B per lane. LDS dest must be wave-uniform base + lane*16.
DEVI void gl_lds16(const u16* g, u16* l) {
  __builtin_amdgcn_global_load_lds(
      (const __attribute__((address_space(1))) void*)g,
      (__attribute__((address_space(3))) void*)l, 16, 0, 0);
}

#define LGKM0() __asm__ volatile("s_waitcnt lgkmcnt(0)" ::: "memory")
#define VM0()   __asm__ volatile("s_waitcnt vmcnt(0)" ::: "memory")
#define BARRIER()                       \
  do {                                  \
    __builtin_amdgcn_s_barrier();       \
    __asm__ volatile("" ::: "memory");  \
  } while (0)

// ---------------- fused prep: z 0..2 cast fp32->fp16 (q/k/v), z 3..6 W^T ----------------
__global__ __launch_bounds__(256) void prep(
    const float* __restrict__ q, const float* __restrict__ k,
    const float* __restrict__ v, u16* __restrict__ qb, u16* __restrict__ kb,
    u16* __restrict__ vb, const float* __restrict__ W0,
    const float* __restrict__ W1, const float* __restrict__ W2,
    const float* __restrict__ W3, u16* __restrict__ T0, u16* __restrict__ T1,
    u16* __restrict__ T2, u16* __restrict__ T3, int n) {
  __shared__ float tile[32][33];
  const int z = blockIdx.z;
  if (z < 3) {
    const float* in = z == 0 ? q : (z == 1 ? k : v);
    u16* out = z == 0 ? qb : (z == 1 ? kb : vb);
    int i = (blockIdx.x * 256 + threadIdx.x) * 4;
    if (i + 3 < n) {
      const float4 vv = *(const float4*)(in + i);
      ushort4 o;
      o.x = f2h_bits(vv.x); o.y = f2h_bits(vv.y);
      o.z = f2h_bits(vv.z); o.w = f2h_bits(vv.w);
      *(ushort4*)(out + i) = o;
    }
    return;
  }
  if (blockIdx.x >= 1024) return;  // transpose needs 32x32 blocks only
  const int w = z - 3;
  const float* W = w == 0 ? W0 : (w == 1 ? W1 : (w == 2 ? W2 : W3));
  u16* Wt = w == 0 ? T0 : (w == 1 ? T1 : (w == 2 ? T2 : T3));
  const int bx = (blockIdx.x & 31) * 32;
  const int by = (blockIdx.x >> 5) * 32;
  const int x = threadIdx.x & 31;
  const int y0 = threadIdx.x >> 5;  // 0..7
#pragma unroll
  for (int i = y0; i < 32; i += 8)
    tile[i][x] = W[(size_t)(by + i) * 1024 + bx + x];
  __syncthreads();
#pragma unroll
  for (int i = y0; i < 32; i += 8)
    Wt[(size_t)(bx + i) * 1024 + by + x] = f2h_bits(tile[x][i]);
}

// ---------------- GEMM body: C[4096x1024] = A[4096x1024] x Bt[1024x1024]^T ----------------
// Tile 128x128, 2x2 waves. Grid per z is (8, 32); XCD-chunked bijective swizzle
// (nwg=256 % 8 == 0): hw g2 -> L = (g2&7)*32 + (g2>>3); by'=L/8, bx'=L%8.
// 3-buffer depth-2 gl_lds pipeline: stage(kt+2) issued while computing kt;
// counted s_waitcnt vmcnt(4) (never 0 mid-loop) + raw barriers.
// 32-elem rows in LDS = 4 chunks of 8; chunk swizzle p = c ^ ((row>>1)&3).
// mode 0: fp32 out; mode 1: fp16 out row-major; mode 2: fp16 out as Vt[b][h][d][s]
DEVI void gemm_body(const u16* __restrict__ A, const u16* __restrict__ Bt,
                    void* __restrict__ Cout, int mode, u16* As, u16* Bs) {
  constexpr int K = 1024, N = 1024;
  const int t = threadIdx.x;
  const int lane = t & 63;
  const int quad = lane >> 4;
  const int l16 = lane & 15;
  const int wid = t >> 6;
  // XCD-chunked swizzle: XCD x hosts output rows by' = 4x..4x+3 (all bx)
  const int g2 = blockIdx.y * 8 + blockIdx.x;
  const int L = (g2 & 7) * 32 + (g2 >> 3);
  const int mBase = (L >> 3) * 128;
  const int nBase = (L & 7) * 128;
  const int wM = (wid >> 1) * 64;
  const int wN = (wid & 1) * 64;
  const int aswz = (quad ^ ((l16 >> 1) & 3)) << 3;  // frag-read physical col

  f32x4 acc[4][4];
#pragma unroll
  for (int i = 0; i < 4; ++i)
#pragma unroll
    for (int j = 0; j < 4; ++j) acc[i][j] = (f32x4){0.f, 0.f, 0.f, 0.f};

  // staging: 128x32 f16 tile = 8KB = 512 16B-chunks / 256 thr, A and B each
  auto stage = [&](int kt, u16* Ad, u16* Bd) {
#pragma unroll
    for (int i = 0; i < 2; ++i) {
      const int ci = i * 256 + t;
      const int row = ci >> 2;                              // 4 chunks per 32-elem row
      const int col = (((ci & 3) ^ ((ci >> 3) & 3)) << 3);  // staging-side swizzle
      gl_lds16(A + (size_t)(mBase + row) * K + kt * 32 + col, Ad + ci * 8);
      gl_lds16(Bt + (size_t)(nBase + row) * K + kt * 32 + col, Bd + ci * 8);
    }
  };

  u16 *a0 = As, *a1 = As + 4096, *a2 = As + 8192;
  u16 *b0 = Bs, *b1 = Bs + 4096, *b2 = Bs + 8192;

  // prologue: stage tiles 0,1; unconditional full drain (once per block)
  stage(0, a0, b0);
  stage(1, a1, b1);
  VM0();
  BARRIER();

  for (int kt = 0; kt < K / 32; ++kt) {
    if (kt + 2 < K / 32) stage(kt + 2, a2, b2);

    half8 a[4], b[4];
#pragma unroll
    for (int mi = 0; mi < 4; ++mi)
      a[mi] = *(const half8*)(a0 + (wM + mi * 16 + l16) * 32 + aswz);
#pragma unroll
    for (int ni = 0; ni < 4; ++ni)
      b[ni] = *(const half8*)(b0 + (wN + ni * 16 + l16) * 32 + aswz);
#pragma unroll
    for (int mi = 0; mi < 4; ++mi)
#pragma unroll
      for (int ni = 0; ni < 4; ++ni)
        acc[mi][ni] = MFMA16(a[mi], b[ni], acc[mi][ni]);

    if (kt + 1 < K / 32) {
      // outstanding gl_lds here: kt+1's 4 (+ kt+2's 4 if staged).
      if (kt + 2 < K / 32)
        __asm__ volatile("s_waitcnt vmcnt(4)" ::: "memory");  // kt+1 landed, kt+2 flying
      else
        VM0();  // tail: last tile landed
      __builtin_amdgcn_sched_barrier(0);
      LGKM0();  // own frag ds_reads done -> safe for others to overwrite old buf
      BARRIER();
    }
    u16* ta = a0; a0 = a1; a1 = a2; a2 = ta;
    u16* tb = b0; b0 = b1; b1 = b2; b2 = tb;
  }

  // epilogue. C/D layout: row = quad*4 + reg, col = lane&15 (m89/m91-verified)
#pragma unroll
  for (int mi = 0; mi < 4; ++mi) {
#pragma unroll
    for (int ni = 0; ni < 4; ++ni) {
#pragma unroll
      for (int r = 0; r < 4; ++r) {
        const int m = mBase + wM + mi * 16 + quad * 4 + r;
        const int n = nBase + wN + ni * 16 + l16;
        const float v = acc[mi][ni][r];
        if (mode == 0) {
          ((float*)Cout)[(size_t)m * N + n] = v;
        } else if (mode == 1) {
          ((u16*)Cout)[(size_t)m * N + n] = f2h_bits(v);
        } else {
          // Vt[(b*1024 + n)][s], b = m>>11, s = m&2047, S=2048
          ((u16*)Cout)[(((size_t)(m >> 11) * 1024 + n) << 11) | (size_t)(m & 2047)] = f2h_bits(v);
        }
      }
    }
  }
}

__global__ __launch_bounds__(256) void proj_qkv(
    const u16* __restrict__ qb, const u16* __restrict__ kb, const u16* __restrict__ vb,
    const u16* __restrict__ Wqt, const u16* __restrict__ Wkt, const u16* __restrict__ Wvt,
    u16* __restrict__ Qp, u16* __restrict__ Kp, u16* __restrict__ Vtp) {
  __shared__ u16 As[3 * 128 * 32];  // 24 KB (3 buffers)
  __shared__ u16 Bs[3 * 128 * 32];  // 24 KB
  const int z = blockIdx.z;
  const u16* A = z == 0 ? qb : (z == 1 ? kb : vb);
  const u16* Bt = z == 0 ? Wqt : (z == 1 ? Wkt : Wvt);
  void* C = z == 0 ? (void*)Qp : (z == 1 ? (void*)Kp : (void*)Vtp);
  gemm_body(A, Bt, C, z == 2 ? 2 : 1, As, Bs);
}

__global__ __launch_bounds__(256) void gemm_out(const u16* __restrict__ Ao,
                                                const u16* __restrict__ Wot,
                                                float* __restrict__ out) {
  __shared__ u16 As[3 * 128 * 32];
  __shared__ u16 Bs[3 * 128 * 32];
  gemm_body(Ao, Wot, out, 0, As, Bs);
}

// ---------------- flash attention + ALiBi, no-max exp2 softmax ----------------
// grid (32 qtiles, 16 y, 2 batch), 256 thr = 4 waves x 16 q-rows, K-tile 64,
// double-buffered K/V, stage-early pipeline w/ ONE barrier per tile.
// Head map h = (y<8 ? 15-y : y-8): co-resident CU block-pairs (y,y+8) get a
// heavy+light head pair -> per-CU k-tile load ~54..70 (was 38..86).
// Q is register-resident (staged once via the Ps buffer; wave-private rows).
// Ks/Vs rows are 64 f16 = 8 chunks; chunk swizzle p = c ^ (row&7) applied on
// the global side of the staging load, undone at frag-read time -> 2-way banks.
// ALiBi skip: tile dropped when sl2*dist > 30 (neglected mass < 2^-15 of l).
__global__ __launch_bounds__(256, 4) void flash_alibi(
    const u16* __restrict__ Qg, const u16* __restrict__ Kg,
    const u16* __restrict__ Vtg, u16* __restrict__ Og) {
  constexpr int S = 2048, Dm = 1024, HD = 64;
  __shared__ u16 Ks[2][64 * 64];   // 16 KB double-buffered
  __shared__ u16 Vs[2][64 * 64];   // 16 KB double-buffered, Vs[d][k]
  __shared__ u16 Ps[64 * 64];      // 8 KB; stages Q in prologue, then P tiles
  const int t = threadIdx.x, lane = t & 63, wid = t >> 6;  // wid 0..3
  const int quad = lane >> 4, l16 = lane & 15;
  const int qt = blockIdx.x, b = blockIdx.z;
  const int y = blockIdx.y;
  const int h = (y < 8) ? (15 - y) : (y - 8);  // heavy+light pairing on CUs
  const int qBase = qt * 64;
  const size_t qRow0 = (size_t)b * S + qBase;
  const float sl2 = __builtin_amdgcn_exp2f(-0.5f * (float)(h + 1)) * 1.44269504f;
  const float sc2 = 0.125f * 1.44269504f;  // (1/sqrt(64))*log2(e)
  const int Di = (int)(30.0f / sl2);
  const int ktLo = max(0, (qBase - Di) >> 6);
  const int ktHi = min(31, (qBase + 63 + Di) >> 6);
  const int cswz = ((l16 & 7) << 3);  // frag-read chunk xor (x8 elems)
  const int pRowBase = wid * 16;      // this wave's private 16-row P region

  // prologue staging: Q tile -> Ps (64 rows x 8 chunks = 512 chunks / 256 thr)
#pragma unroll
  for (int i = 0; i < 2; ++i) {
    const int ci = i * 256 + t;
    const int row = ci >> 3, col = (((ci & 7) ^ (row & 7)) << 3);
    gl_lds16(Qg + (qRow0 + row) * Dm + h * HD + col, Ps + ci * 8);
  }
  // prologue staging: K/V tile ktLo into buffer 0
  {
    const int kB = ktLo * 64;
#pragma unroll
    for (int i = 0; i < 2; ++i) {
      const int ci = i * 256 + t;
      const int row = ci >> 3, col = (((ci & 7) ^ (row & 7)) << 3);
      gl_lds16(Kg + ((size_t)b * S + kB + row) * Dm + h * HD + col, Ks[0] + ci * 8);
      gl_lds16(Vtg + ((size_t)(b * 16 + h) * HD + row) * S + kB + col, Vs[0] + ci * 8);
    }
  }

  // ALiBi row bias (constant over kt): bi[r] = sl2 * global_q_row
  float bi[4];
#pragma unroll
  for (int r = 0; r < 4; ++r)
    bi[r] = sl2 * (float)(qBase + wid * 16 + quad * 4 + r);

  f32x4 acc_o[4];
#pragma unroll
  for (int nd = 0; nd < 4; ++nd) acc_o[nd] = (f32x4){0.f, 0.f, 0.f, 0.f};
  float lrow[4] = {0.f, 0.f, 0.f, 0.f};

  __syncthreads();  // drains vmcnt: Q + first K/V tile resident

  // Q -> registers. Wave w reads only rows [16w, 16w+16) of Ps == its own P
  // region, so no cross-wave hazard with later P writes; DS ops are wave-ordered
  // so these reads complete before this wave's own softmax stores below.
  half8 aq[2];
#pragma unroll
  for (int ks = 0; ks < 2; ++ks) {
    const int ck = ((ks * 4 + quad) << 3) ^ cswz;
    aq[ks] = *(const half8*)(Ps + (pRowBase + l16) * HD + ck);
  }

  int bb = 0;
  for (int kt = ktLo; kt <= ktHi; ++kt) {
    const int kB = kt * 64;
    // stage NEXT tile into the other buffer, latency hidden under this tile's compute
    if (kt < ktHi) {
      const int kBn = kB + 64;
#pragma unroll
      for (int i = 0; i < 2; ++i) {
        const int ci = i * 256 + t;
        const int row = ci >> 3, col = (((ci & 7) ^ (row & 7)) << 3);
        gl_lds16(Kg + ((size_t)b * S + kBn + row) * Dm + h * HD + col, Ks[bb ^ 1] + ci * 8);
        gl_lds16(Vtg + ((size_t)(b * 16 + h) * HD + row) * S + kBn + col, Vs[bb ^ 1] + ci * 8);
      }
    }

    const u16* Kb = Ks[bb];
    const u16* Vb = Vs[bb];

    // S = Q K^T : per wave 16q x 64k  (Q frags from registers)
    f32x4 s4[4];
#pragma unroll
    for (int ni = 0; ni < 4; ++ni) s4[ni] = (f32x4){0.f, 0.f, 0.f, 0.f};
    __builtin_amdgcn_s_setprio(1);
#pragma unroll
    for (int ks = 0; ks < 2; ++ks) {
      const int ck = ((ks * 4 + quad) << 3) ^ cswz;
#pragma unroll
      for (int ni = 0; ni < 4; ++ni) {
        const half8 bk = *(const half8*)(Kb + (ni * 16 + l16) * HD + ck);
        s4[ni] = MFMA16(aq[ks], bk, s4[ni]);
      }
    }
    __builtin_amdgcn_s_setprio(0);

    // p = exp2(s*sc2 - |bi - bj|); per-lane l partials; write swizzled P
    float bj[4];
#pragma unroll
    for (int ni = 0; ni < 4; ++ni) bj[ni] = sl2 * (float)(kB + ni * 16 + l16);
#pragma unroll
    for (int r = 0; r < 4; ++r) {
      float rs = 0.f;
      const int prow = (pRowBase + quad * 4 + r) * 64;
#pragma unroll
      for (int ni = 0; ni < 4; ++ni) {
        const float d = fabsf(bi[r] - bj[ni]);
        const float p = __builtin_amdgcn_exp2f(s4[ni][r] * sc2 - d);
        rs += p;
        Ps[prow + ((ni * 16 + l16) ^ (quad << 4))] = f2h_bits(p);
      }
      lrow[r] += rs;
    }
    // P region is per-wave: wave-local LDS drain is sufficient (no block barrier)
    __asm__ volatile("s_waitcnt lgkmcnt(0)" ::: "memory");

    // O += P V : P A-frags (swizzled, 16B-contiguous), V B-frags
    __builtin_amdgcn_s_setprio(1);
#pragma unroll
    for (int ks = 0; ks < 2; ++ks) {
      const int pk = (ks * 32 + quad * 8) ^ ((l16 & 12) << 2);
      const int ck = ((ks * 4 + quad) << 3) ^ cswz;
      const half8 aP = *(const half8*)(Ps + (pRowBase + l16) * 64 + pk);
#pragma unroll
      for (int nd = 0; nd < 4; ++nd) {
        const half8 bv = *(const half8*)(Vb + (nd * 16 + l16) * HD + ck);
        acc_o[nd] = MFMA16(aP, bv, acc_o[nd]);
      }
    }
    __builtin_amdgcn_s_setprio(0);

    __syncthreads();  // ONE barrier/iter: drains next-tile stage (vmcnt) + all LDS reads
    bb ^= 1;
  }

  // epilogue: reduce l across the 16 lanes sharing each row, O /= l, write f16
#pragma unroll
  for (int r = 0; r < 4; ++r) {
    float l = lrow[r];
    l += __shfl_xor(l, 1);
    l += __shfl_xor(l, 2);
    l += __shfl_xor(l, 4);
    l += __shfl_xor(l, 8);
    const float inv = 1.f / l;
    const int rloc = wid * 16 + quad * 4 + r;
#pragma unroll
    for (int nd = 0; nd < 4; ++nd)
      Og[(qRow0 + rloc) * Dm + h * HD + nd * 16 + l16] = f2h_bits(acc_o[nd][r] * inv);
  }
}

extern "C" void kernel_launch(void* const* d_in, const int* in_sizes, int n_in,
                              void* d_out, int out_size, void* d_ws, size_t ws_size,
                              hipStream_t stream) {
  const float* q  = (const float*)d_in[0];
  const float* k  = (const float*)d_in[1];
  const float* v  = (const float*)d_in[2];
  const float* Wq = (const float*)d_in[3];
  const float* Wk = (const float*)d_in[4];
  const float* Wv = (const float*)d_in[5];
  const float* Wo = (const float*)d_in[6];
  char* ws = (char*)d_ws;
  const size_t MB = 1ull << 20;
  // workspace map (64 MB total)
  u16* qb  = (u16*)(ws + 0 * MB);    // 8 MB  q fp16
  u16* kb  = (u16*)(ws + 8 * MB);    // 8 MB
  u16* vb  = (u16*)(ws + 16 * MB);   // 8 MB
  u16* Wqt = (u16*)(ws + 24 * MB);   // 2 MB  W^T fp16
  u16* Wkt = (u16*)(ws + 26 * MB);
  u16* Wvt = (u16*)(ws + 28 * MB);
  u16* Wot = (u16*)(ws + 30 * MB);
  u16* Qp  = (u16*)(ws + 32 * MB);   // 8 MB  Q proj [4096][1024]
  u16* Kp  = (u16*)(ws + 40 * MB);   // 8 MB
  u16* Vtp = (u16*)(ws + 48 * MB);   // 8 MB  V proj transposed [b][h][64][2048]
  u16* Ao  = (u16*)(ws + 56 * MB);   // 8 MB  attention out [4096][1024]

  const int n = 2 * 2048 * 1024;
  prep<<<dim3(4096, 1, 7), 256, 0, stream>>>(q, k, v, qb, kb, vb,
                                             Wq, Wk, Wv, Wo, Wqt, Wkt, Wvt, Wot, n);
  proj_qkv<<<dim3(8, 32, 3), 256, 0, stream>>>(qb, kb, vb, Wqt, Wkt, Wvt, Qp, Kp, Vtp);
  flash_alibi<<<dim3(32, 16, 2), 256, 0, stream>>>(Qp, Kp, Vtp, Ao);
  gemm_out<<<dim3(8, 32), 256, 0, stream>>>(Ao, Wot, (float*)d_out);
}